// Round 1
// baseline (657.182 us; speedup 1.0000x reference)
//
#include <hip/hip_runtime.h>
#include <hip/hip_bf16.h>

#define NN 100000
#define EE 1600000
#define NB1 391   // ceil(NN/256)

// ---------------- CSR build ----------------

__global__ void k_degree(const int* __restrict__ ei, int* __restrict__ deg) {
    int e = blockIdx.x * 256 + threadIdx.x;
    if (e < EE) atomicAdd(&deg[ei[EE + e]], 1);
}

__global__ void k_scan1(const int* __restrict__ deg, int* __restrict__ rs, int* __restrict__ bsum) {
    __shared__ int s[256];
    int tid = threadIdx.x;
    int i = blockIdx.x * 256 + tid;
    int v = (i < NN) ? deg[i] : 0;
    s[tid] = v;
    __syncthreads();
    for (int off = 1; off < 256; off <<= 1) {
        int t = (tid >= off) ? s[tid - off] : 0;
        __syncthreads();
        if (tid >= off) s[tid] += t;
        __syncthreads();
    }
    if (i < NN) rs[i] = s[tid] - v;          // exclusive within block
    if (tid == 255) bsum[blockIdx.x] = s[255];
}

__global__ void k_scan2(int* __restrict__ bsum) {
    __shared__ int s[512];
    int tid = threadIdx.x;
    int v = (tid < NB1) ? bsum[tid] : 0;
    s[tid] = v;
    __syncthreads();
    for (int off = 1; off < 512; off <<= 1) {
        int t = (tid >= off) ? s[tid - off] : 0;
        __syncthreads();
        if (tid >= off) s[tid] += t;
        __syncthreads();
    }
    if (tid < NB1) bsum[tid] = s[tid] - v;   // exclusive block offsets
}

__global__ void k_scan3(int* __restrict__ rs, const int* __restrict__ bsum, int* __restrict__ cursor) {
    int i = blockIdx.x * 256 + threadIdx.x;
    if (i < NN) {
        int v = rs[i] + bsum[blockIdx.x];
        rs[i] = v;
        cursor[i] = v;
    }
    if (i == 0) rs[NN] = EE;
}

__global__ void k_bucket(const int* __restrict__ ei, int* __restrict__ cursor, int* __restrict__ esrc) {
    int e = blockIdx.x * 256 + threadIdx.x;
    if (e < EE) {
        int dst = ei[EE + e];
        int pos = atomicAdd(&cursor[dst], 1);
        esrc[pos] = ei[e];
    }
}

// ---------------- aggregation: mean over incoming neighbors ----------------
// 16 threads per node, float4 per thread.
__global__ void k_aggregate(const float* __restrict__ x, const int* __restrict__ rs,
                            const int* __restrict__ esrc, float* __restrict__ mean) {
    int gid = blockIdx.x * 256 + threadIdx.x;
    int node = gid >> 4;
    if (node >= NN) return;
    int c = gid & 15;
    int s0 = rs[node], s1 = rs[node + 1];
    const float4* x4 = (const float4*)x;
    float4 acc = make_float4(0.f, 0.f, 0.f, 0.f);
    int p = s0;
    for (; p + 2 <= s1; p += 2) {
        int sa = esrc[p], sb = esrc[p + 1];
        float4 va = x4[sa * 16 + c];
        float4 vb = x4[sb * 16 + c];
        acc.x += va.x + vb.x; acc.y += va.y + vb.y;
        acc.z += va.z + vb.z; acc.w += va.w + vb.w;
    }
    if (p < s1) {
        int sa = esrc[p];
        float4 va = x4[sa * 16 + c];
        acc.x += va.x; acc.y += va.y; acc.z += va.z; acc.w += va.w;
    }
    int cnt = s1 - s0; if (cnt < 1) cnt = 1;
    float inv = 1.0f / (float)cnt;
    acc.x *= inv; acc.y *= inv; acc.z *= inv; acc.w *= inv;
    ((float4*)mean)[node * 16 + c] = acc;
}

// ---------------- SAGE layer (D_H=64): GEMM K=128 + bias + L2-norm + BN stats ----------------
// block = 256 threads, tile = 64 nodes x 64 features, 4x4 micro-tile per thread.
__global__ __launch_bounds__(256, 2)
void k_sage64(const float* __restrict__ A1,   // mean  (N,64)
              const float* A2,                // x / h (N,64) -- may alias out
              const float* __restrict__ Wl, const float* __restrict__ Wr,
              const float* __restrict__ bias,
              float* out,                     // (N,64) -- may alias A2
              float* __restrict__ sumf, float* __restrict__ ssqf) {
    __shared__ float Alds[128 * 64];
    __shared__ float Wlds[128 * 64];
    const int tid = threadIdx.x;
    const int base = blockIdx.x * 64;

    // stage W transposed [k][f], lanes vary f fastest (bank = f%32, conflict-free)
    {
        const float4* Wl4 = (const float4*)Wl;
        const float4* Wr4 = (const float4*)Wr;
#pragma unroll
        for (int i = 0; i < 8; ++i) {
            int idx = i * 256 + tid;
            int f = idx & 63, c = idx >> 6;            // c in [0,32)
            float4 w = (c < 16) ? Wl4[f * 16 + c] : Wr4[f * 16 + (c - 16)];
            int k0 = c * 4;
            Wlds[(k0 + 0) * 64 + f] = w.x;
            Wlds[(k0 + 1) * 64 + f] = w.y;
            Wlds[(k0 + 2) * 64 + f] = w.z;
            Wlds[(k0 + 3) * 64 + f] = w.w;
        }
    }
    // stage A transposed [k][node], lanes vary node fastest (bank = node%32, conflict-free)
    {
        const float4* A14 = (const float4*)A1;
        const float4* A24 = (const float4*)A2;
#pragma unroll
        for (int i = 0; i < 8; ++i) {
            int idx = i * 256 + tid;
            int node = idx & 63, c = idx >> 6;
            int gn = base + node; if (gn > NN - 1) gn = NN - 1;
            float4 a = (c < 16) ? A14[gn * 16 + c] : A24[gn * 16 + (c - 16)];
            int k0 = c * 4;
            Alds[(k0 + 0) * 64 + node] = a.x;
            Alds[(k0 + 1) * 64 + node] = a.y;
            Alds[(k0 + 2) * 64 + node] = a.z;
            Alds[(k0 + 3) * 64 + node] = a.w;
        }
    }
    __syncthreads();

    const int fg = tid & 15;    // feature group: f = fg*4..fg*4+3
    const int ng = tid >> 4;    // node group:    n = ng*4..ng*4+3

    float acc[4][4] = {};
#pragma unroll 8
    for (int k = 0; k < 128; ++k) {
        const float4 a = *(const float4*)(Alds + k * 64 + (ng << 2));
        const float4 w = *(const float4*)(Wlds + k * 64 + (fg << 2));
        const float av[4] = {a.x, a.y, a.z, a.w};
        const float wv[4] = {w.x, w.y, w.z, w.w};
#pragma unroll
        for (int i = 0; i < 4; ++i)
#pragma unroll
            for (int j = 0; j < 4; ++j)
                acc[i][j] = fmaf(av[i], wv[j], acc[i][j]);
    }

    // epilogue: bias, row L2-norm, write, BN stat partials
    const float4 b4 = ((const float4*)bias)[fg];
    float ss[4];
#pragma unroll
    for (int i = 0; i < 4; ++i) {
        acc[i][0] += b4.x; acc[i][1] += b4.y; acc[i][2] += b4.z; acc[i][3] += b4.w;
        ss[i] = acc[i][0] * acc[i][0] + acc[i][1] * acc[i][1] +
                acc[i][2] * acc[i][2] + acc[i][3] * acc[i][3];
    }
#pragma unroll
    for (int m = 1; m <= 8; m <<= 1) {
#pragma unroll
        for (int i = 0; i < 4; ++i) ss[i] += __shfl_xor(ss[i], m, 64);
    }
    float sj[4] = {0.f, 0.f, 0.f, 0.f}, qj[4] = {0.f, 0.f, 0.f, 0.f};
#pragma unroll
    for (int i = 0; i < 4; ++i) {
        float inv = 1.0f / fmaxf(sqrtf(ss[i]), 1e-12f);
        int gn = base + (ng << 2) + i;
        bool valid = (gn < NN);
        float o0 = acc[i][0] * inv, o1 = acc[i][1] * inv;
        float o2 = acc[i][2] * inv, o3 = acc[i][3] * inv;
        if (valid) {
            ((float4*)out)[gn * 16 + fg] = make_float4(o0, o1, o2, o3);
            sj[0] += o0; sj[1] += o1; sj[2] += o2; sj[3] += o3;
            qj[0] += o0 * o0; qj[1] += o1 * o1; qj[2] += o2 * o2; qj[3] += o3 * o3;
        }
    }
    // reduce over node groups within wave (lanes xor 16, 32)
#pragma unroll
    for (int m = 16; m <= 32; m <<= 1) {
#pragma unroll
        for (int j = 0; j < 4; ++j) {
            sj[j] += __shfl_xor(sj[j], m, 64);
            qj[j] += __shfl_xor(qj[j], m, 64);
        }
    }
    __syncthreads();                  // done reading Alds; reuse for block stats
    float* sblk = Alds;               // [0,64)
    float* qblk = Alds + 64;          // [64,128)
    if (tid < 128) Alds[tid] = 0.0f;
    __syncthreads();
    if ((tid & 63) < 16) {
#pragma unroll
        for (int j = 0; j < 4; ++j) {
            atomicAdd(&sblk[fg * 4 + j], sj[j]);
            atomicAdd(&qblk[fg * 4 + j], qj[j]);
        }
    }
    __syncthreads();
    if (tid < 64) {
        atomicAdd(&sumf[tid], sblk[tid]);
        atomicAdd(&ssqf[tid], qblk[tid]);
    }
}

// ---------------- BN finalize + apply ----------------

__global__ void k_bnfin(const float* __restrict__ sumf, const float* __restrict__ ssqf,
                        const float* __restrict__ g, const float* __restrict__ be,
                        float* __restrict__ scale, float* __restrict__ shift) {
    int f = threadIdx.x;  // 64
    float mu = sumf[f] / (float)NN;
    float var = ssqf[f] / (float)NN - mu * mu;
    var = fmaxf(var, 0.0f);
    float sc = g[f] / sqrtf(var + 1e-5f);
    scale[f] = sc;
    shift[f] = be[f] - mu * sc;
}

__global__ void k_bnapply(float* __restrict__ h, const float* __restrict__ scale,
                          const float* __restrict__ shift) {
    int i = blockIdx.x * 256 + threadIdx.x;  // over NN*16 float4
    if (i >= NN * 16) return;
    int fg = i & 15;
    float4 sc = ((const float4*)scale)[fg];
    float4 sh = ((const float4*)shift)[fg];
    float4 v = ((float4*)h)[i];
    v.x = fmaxf(fmaf(v.x, sc.x, sh.x), 0.f);
    v.y = fmaxf(fmaf(v.y, sc.y, sh.y), 0.f);
    v.z = fmaxf(fmaf(v.z, sc.z, sh.z), 0.f);
    v.w = fmaxf(fmaf(v.w, sc.w, sh.w), 0.f);
    ((float4*)h)[i] = v;
}

// ---------------- final layer (D_OUT=10) ----------------
// one wave per node: lane k holds input k, shuffle-reduce each of 10 dots.
__global__ __launch_bounds__(256)
void k_sage10(const float* __restrict__ A1, const float* __restrict__ A2,
              const float* __restrict__ Wl, const float* __restrict__ Wr,
              const float* __restrict__ bias, float* __restrict__ out) {
    __shared__ float wl[640], wr[640], bb[16];
    int tid = threadIdx.x;
    for (int i = tid; i < 640; i += 256) { wl[i] = Wl[i]; wr[i] = Wr[i]; }
    if (tid < 10) bb[tid] = bias[tid];
    __syncthreads();
    int lane = tid & 63, w = tid >> 6;
    for (int node = blockIdx.x * 4 + w; node < NN; node += gridDim.x * 4) {
        float m = A1[node * 64 + lane];
        float h = A2[node * 64 + lane];
        float r = 0.f;
#pragma unroll
        for (int f = 0; f < 10; ++f) {
            float p = fmaf(m, wl[f * 64 + lane], h * wr[f * 64 + lane]);
            p += __shfl_xor(p, 32, 64);
            p += __shfl_xor(p, 16, 64);
            p += __shfl_xor(p, 8, 64);
            p += __shfl_xor(p, 4, 64);
            p += __shfl_xor(p, 2, 64);
            p += __shfl_xor(p, 1, 64);
            if (lane == f) r = p + bb[f];
        }
        if (lane < 10) out[node * 10 + lane] = r;
    }
}

// ---------------- launch ----------------

extern "C" void kernel_launch(void* const* d_in, const int* in_sizes, int n_in,
                              void* d_out, int out_size, void* d_ws, size_t ws_size,
                              hipStream_t stream) {
    const float* x   = (const float*)d_in[0];
    const int*   ei  = (const int*)d_in[1];
    const float* Wl1 = (const float*)d_in[2];
    const float* Wr1 = (const float*)d_in[3];
    const float* b1  = (const float*)d_in[4];
    const float* g1  = (const float*)d_in[5];
    const float* be1 = (const float*)d_in[6];
    const float* Wl2 = (const float*)d_in[7];
    const float* Wr2 = (const float*)d_in[8];
    const float* b2  = (const float*)d_in[9];
    const float* g2  = (const float*)d_in[10];
    const float* be2 = (const float*)d_in[11];
    const float* Wl3 = (const float*)d_in[12];
    const float* Wr3 = (const float*)d_in[13];
    const float* b3  = (const float*)d_in[14];
    float* out = (float*)d_out;

    char* w = (char*)d_ws;
    auto alloc = [&](size_t bytes) -> void* {
        void* p = (void*)w;
        w += (bytes + 255) & ~(size_t)255;
        return p;
    };
    int*   deg    = (int*)alloc((size_t)NN * 4);
    int*   rs     = (int*)alloc((size_t)(NN + 1) * 4);
    int*   cursor = (int*)alloc((size_t)NN * 4);
    int*   bsum   = (int*)alloc(512 * 4);
    int*   esrc   = (int*)alloc((size_t)EE * 4);
    float* mean   = (float*)alloc((size_t)NN * 64 * 4);
    float* h1     = (float*)alloc((size_t)NN * 64 * 4);
    float* stats  = (float*)alloc(256 * 4);  // sum1, ssq1, sum2, ssq2
    float* scsh   = (float*)alloc(256 * 4);  // scale1, shift1, scale2, shift2

    hipMemsetAsync(deg, 0, (size_t)NN * 4, stream);
    hipMemsetAsync(stats, 0, 256 * 4, stream);

    k_degree<<<EE / 256, 256, 0, stream>>>(ei, deg);
    k_scan1<<<NB1, 256, 0, stream>>>(deg, rs, bsum);
    k_scan2<<<1, 512, 0, stream>>>(bsum);
    k_scan3<<<NB1, 256, 0, stream>>>(rs, bsum, cursor);
    k_bucket<<<EE / 256, 256, 0, stream>>>(ei, cursor, esrc);

    const int aggBlocks = (NN * 16) / 256;      // 6250
    const int sageBlocks = (NN + 63) / 64;      // 1563

    // layer 1
    k_aggregate<<<aggBlocks, 256, 0, stream>>>(x, rs, esrc, mean);
    k_sage64<<<sageBlocks, 256, 0, stream>>>(mean, x, Wl1, Wr1, b1, h1, stats + 0, stats + 64);
    k_bnfin<<<1, 64, 0, stream>>>(stats + 0, stats + 64, g1, be1, scsh + 0, scsh + 64);
    k_bnapply<<<aggBlocks, 256, 0, stream>>>(h1, scsh + 0, scsh + 64);

    // layer 2 (h2 written in place over h1)
    k_aggregate<<<aggBlocks, 256, 0, stream>>>(h1, rs, esrc, mean);
    k_sage64<<<sageBlocks, 256, 0, stream>>>(mean, h1, Wl2, Wr2, b2, h1, stats + 128, stats + 192);
    k_bnfin<<<1, 64, 0, stream>>>(stats + 128, stats + 192, g2, be2, scsh + 128, scsh + 192);
    k_bnapply<<<aggBlocks, 256, 0, stream>>>(h1, scsh + 128, scsh + 192);

    // layer 3
    k_aggregate<<<aggBlocks, 256, 0, stream>>>(h1, rs, esrc, mean);
    k_sage10<<<4096, 256, 0, stream>>>(mean, h1, Wl3, Wr3, b3, out);
}

// Round 2
// 580.704 us; speedup vs baseline: 1.1317x; 1.1317x over previous
//
#include <hip/hip_runtime.h>
#include <hip/hip_bf16.h>

#define NN 100000
#define EE 1600000
#define NB1 391    // ceil(NN/256)
#define BSZ 512    // dst-nodes per coarse bucket
#define NBKT 196   // ceil(NN/BSZ)
#define CHUNK 8192 // edges per k_coarse block
#define NCH 196    // ceil(EE/CHUNK)

// ---------------- CSR build ----------------

__global__ void k_degree(const int* __restrict__ ei, int* __restrict__ deg) {
    int e = blockIdx.x * 256 + threadIdx.x;
    if (e < EE) atomicAdd(&deg[ei[EE + e]], 1);
}

__global__ void k_scan1(const int* __restrict__ deg, int* __restrict__ rs, int* __restrict__ bsum) {
    __shared__ int s[256];
    int tid = threadIdx.x;
    int i = blockIdx.x * 256 + tid;
    int v = (i < NN) ? deg[i] : 0;
    s[tid] = v;
    __syncthreads();
    for (int off = 1; off < 256; off <<= 1) {
        int t = (tid >= off) ? s[tid - off] : 0;
        __syncthreads();
        if (tid >= off) s[tid] += t;
        __syncthreads();
    }
    if (i < NN) rs[i] = s[tid] - v;          // exclusive within block
    if (tid == 255) bsum[blockIdx.x] = s[255];
}

__global__ void k_scan2(int* __restrict__ bsum) {
    __shared__ int s[512];
    int tid = threadIdx.x;
    int v = (tid < NB1) ? bsum[tid] : 0;
    s[tid] = v;
    __syncthreads();
    for (int off = 1; off < 512; off <<= 1) {
        int t = (tid >= off) ? s[tid - off] : 0;
        __syncthreads();
        if (tid >= off) s[tid] += t;
        __syncthreads();
    }
    if (tid < NB1) bsum[tid] = s[tid] - v;   // exclusive block offsets
}

__global__ void k_scan3(int* __restrict__ rs, const int* __restrict__ bsum) {
    int i = blockIdx.x * 256 + threadIdx.x;
    if (i < NN) rs[i] += bsum[blockIdx.x];
    if (i == 0) rs[NN] = EE;
}

__global__ void k_initcur(const int* __restrict__ rs, int* __restrict__ gcur) {
    int b = threadIdx.x;
    if (b < NBKT) gcur[b] = rs[b * BSZ];
}

// coarse pass: bin edges by dst>>9, per-block LDS histogram + reserved runs.
__global__ __launch_bounds__(256)
void k_coarse(const int* __restrict__ ei, int* __restrict__ gcur, int2* __restrict__ pairs) {
    __shared__ int hist[NBKT];
    __shared__ int base[NBKT];
    __shared__ int curs[NBKT];
    int tid = threadIdx.x;
    int e0 = blockIdx.x * CHUNK;
    int e1 = e0 + CHUNK; if (e1 > EE) e1 = EE;
    for (int i = tid; i < NBKT; i += 256) hist[i] = 0;
    __syncthreads();
    for (int e = e0 + tid; e < e1; e += 256)
        atomicAdd(&hist[ei[EE + e] >> 9], 1);
    __syncthreads();
    for (int i = tid; i < NBKT; i += 256) {
        base[i] = atomicAdd(&gcur[i], hist[i]);
        curs[i] = 0;
    }
    __syncthreads();
    for (int e = e0 + tid; e < e1; e += 256) {
        int src = ei[e];
        int dst = ei[EE + e];
        int b = dst >> 9;
        int off = atomicAdd(&curs[b], 1);
        pairs[base[b] + off] = make_int2(src, dst);
    }
}

// fine pass: one block per coarse bucket; scatter src into the bucket's
// contiguous slice of esrc (L2-local, lines fill completely).
__global__ __launch_bounds__(256)
void k_fine(const int* __restrict__ rs, const int2* __restrict__ pairs, int* __restrict__ esrc) {
    __shared__ int cur[BSZ];
    int b = blockIdx.x;
    int n0 = b * BSZ;
    int n1 = n0 + BSZ; if (n1 > NN) n1 = NN;
    int tid = threadIdx.x;
    for (int i = tid; i < n1 - n0; i += 256) cur[i] = rs[n0 + i];
    __syncthreads();
    int e0 = rs[n0], e1 = rs[n1];
    for (int e = e0 + tid; e < e1; e += 256) {
        int2 p = pairs[e];
        int pos = atomicAdd(&cur[p.y - n0], 1);
        esrc[pos] = p.x;
    }
}

// ---------------- aggregation: mean over incoming neighbors ----------------
// 16 threads per node, float4 per thread.
__global__ void k_aggregate(const float* __restrict__ x, const int* __restrict__ rs,
                            const int* __restrict__ esrc, float* __restrict__ mean) {
    int gid = blockIdx.x * 256 + threadIdx.x;
    int node = gid >> 4;
    if (node >= NN) return;
    int c = gid & 15;
    int s0 = rs[node], s1 = rs[node + 1];
    const float4* x4 = (const float4*)x;
    float4 acc = make_float4(0.f, 0.f, 0.f, 0.f);
    int p = s0;
    for (; p + 2 <= s1; p += 2) {
        int sa = esrc[p], sb = esrc[p + 1];
        float4 va = x4[sa * 16 + c];
        float4 vb = x4[sb * 16 + c];
        acc.x += va.x + vb.x; acc.y += va.y + vb.y;
        acc.z += va.z + vb.z; acc.w += va.w + vb.w;
    }
    if (p < s1) {
        int sa = esrc[p];
        float4 va = x4[sa * 16 + c];
        acc.x += va.x; acc.y += va.y; acc.z += va.z; acc.w += va.w;
    }
    int cnt = s1 - s0; if (cnt < 1) cnt = 1;
    float inv = 1.0f / (float)cnt;
    acc.x *= inv; acc.y *= inv; acc.z *= inv; acc.w *= inv;
    ((float4*)mean)[node * 16 + c] = acc;
}

// ---------------- SAGE layer (D_H=64): GEMM K=128 + bias + L2-norm + BN stats ----------------
__global__ __launch_bounds__(256, 2)
void k_sage64(const float* __restrict__ A1,   // mean  (N,64)
              const float* A2,                // x / h (N,64) -- may alias out
              const float* __restrict__ Wl, const float* __restrict__ Wr,
              const float* __restrict__ bias,
              float* out,                     // (N,64) -- may alias A2
              float* __restrict__ sumf, float* __restrict__ ssqf) {
    __shared__ float Alds[128 * 64];
    __shared__ float Wlds[128 * 64];
    const int tid = threadIdx.x;
    const int base = blockIdx.x * 64;

    {
        const float4* Wl4 = (const float4*)Wl;
        const float4* Wr4 = (const float4*)Wr;
#pragma unroll
        for (int i = 0; i < 8; ++i) {
            int idx = i * 256 + tid;
            int f = idx & 63, c = idx >> 6;            // c in [0,32)
            float4 w = (c < 16) ? Wl4[f * 16 + c] : Wr4[f * 16 + (c - 16)];
            int k0 = c * 4;
            Wlds[(k0 + 0) * 64 + f] = w.x;
            Wlds[(k0 + 1) * 64 + f] = w.y;
            Wlds[(k0 + 2) * 64 + f] = w.z;
            Wlds[(k0 + 3) * 64 + f] = w.w;
        }
    }
    {
        const float4* A14 = (const float4*)A1;
        const float4* A24 = (const float4*)A2;
#pragma unroll
        for (int i = 0; i < 8; ++i) {
            int idx = i * 256 + tid;
            int node = idx & 63, c = idx >> 6;
            int gn = base + node; if (gn > NN - 1) gn = NN - 1;
            float4 a = (c < 16) ? A14[gn * 16 + c] : A24[gn * 16 + (c - 16)];
            int k0 = c * 4;
            Alds[(k0 + 0) * 64 + node] = a.x;
            Alds[(k0 + 1) * 64 + node] = a.y;
            Alds[(k0 + 2) * 64 + node] = a.z;
            Alds[(k0 + 3) * 64 + node] = a.w;
        }
    }
    __syncthreads();

    const int fg = tid & 15;    // feature group: f = fg*4..fg*4+3
    const int ng = tid >> 4;    // node group:    n = ng*4..ng*4+3

    float acc[4][4] = {};
#pragma unroll 8
    for (int k = 0; k < 128; ++k) {
        const float4 a = *(const float4*)(Alds + k * 64 + (ng << 2));
        const float4 w = *(const float4*)(Wlds + k * 64 + (fg << 2));
        const float av[4] = {a.x, a.y, a.z, a.w};
        const float wv[4] = {w.x, w.y, w.z, w.w};
#pragma unroll
        for (int i = 0; i < 4; ++i)
#pragma unroll
            for (int j = 0; j < 4; ++j)
                acc[i][j] = fmaf(av[i], wv[j], acc[i][j]);
    }

    const float4 b4 = ((const float4*)bias)[fg];
    float ss[4];
#pragma unroll
    for (int i = 0; i < 4; ++i) {
        acc[i][0] += b4.x; acc[i][1] += b4.y; acc[i][2] += b4.z; acc[i][3] += b4.w;
        ss[i] = acc[i][0] * acc[i][0] + acc[i][1] * acc[i][1] +
                acc[i][2] * acc[i][2] + acc[i][3] * acc[i][3];
    }
#pragma unroll
    for (int m = 1; m <= 8; m <<= 1) {
#pragma unroll
        for (int i = 0; i < 4; ++i) ss[i] += __shfl_xor(ss[i], m, 64);
    }
    float sj[4] = {0.f, 0.f, 0.f, 0.f}, qj[4] = {0.f, 0.f, 0.f, 0.f};
#pragma unroll
    for (int i = 0; i < 4; ++i) {
        float inv = 1.0f / fmaxf(sqrtf(ss[i]), 1e-12f);
        int gn = base + (ng << 2) + i;
        bool valid = (gn < NN);
        float o0 = acc[i][0] * inv, o1 = acc[i][1] * inv;
        float o2 = acc[i][2] * inv, o3 = acc[i][3] * inv;
        if (valid) {
            ((float4*)out)[gn * 16 + fg] = make_float4(o0, o1, o2, o3);
            sj[0] += o0; sj[1] += o1; sj[2] += o2; sj[3] += o3;
            qj[0] += o0 * o0; qj[1] += o1 * o1; qj[2] += o2 * o2; qj[3] += o3 * o3;
        }
    }
#pragma unroll
    for (int m = 16; m <= 32; m <<= 1) {
#pragma unroll
        for (int j = 0; j < 4; ++j) {
            sj[j] += __shfl_xor(sj[j], m, 64);
            qj[j] += __shfl_xor(qj[j], m, 64);
        }
    }
    __syncthreads();
    float* sblk = Alds;
    float* qblk = Alds + 64;
    if (tid < 128) Alds[tid] = 0.0f;
    __syncthreads();
    if ((tid & 63) < 16) {
#pragma unroll
        for (int j = 0; j < 4; ++j) {
            atomicAdd(&sblk[fg * 4 + j], sj[j]);
            atomicAdd(&qblk[fg * 4 + j], qj[j]);
        }
    }
    __syncthreads();
    if (tid < 64) {
        atomicAdd(&sumf[tid], sblk[tid]);
        atomicAdd(&ssqf[tid], qblk[tid]);
    }
}

// ---------------- BN finalize + apply ----------------

__global__ void k_bnfin(const float* __restrict__ sumf, const float* __restrict__ ssqf,
                        const float* __restrict__ g, const float* __restrict__ be,
                        float* __restrict__ scale, float* __restrict__ shift) {
    int f = threadIdx.x;  // 64
    float mu = sumf[f] / (float)NN;
    float var = ssqf[f] / (float)NN - mu * mu;
    var = fmaxf(var, 0.0f);
    float sc = g[f] / sqrtf(var + 1e-5f);
    scale[f] = sc;
    shift[f] = be[f] - mu * sc;
}

__global__ void k_bnapply(float* __restrict__ h, const float* __restrict__ scale,
                          const float* __restrict__ shift) {
    int i = blockIdx.x * 256 + threadIdx.x;  // over NN*16 float4
    if (i >= NN * 16) return;
    int fg = i & 15;
    float4 sc = ((const float4*)scale)[fg];
    float4 sh = ((const float4*)shift)[fg];
    float4 v = ((float4*)h)[i];
    v.x = fmaxf(fmaf(v.x, sc.x, sh.x), 0.f);
    v.y = fmaxf(fmaf(v.y, sc.y, sh.y), 0.f);
    v.z = fmaxf(fmaf(v.z, sc.z, sh.z), 0.f);
    v.w = fmaxf(fmaf(v.w, sc.w, sh.w), 0.f);
    ((float4*)h)[i] = v;
}

// ---------------- final layer (D_OUT=10) ----------------
__global__ __launch_bounds__(256)
void k_sage10(const float* __restrict__ A1, const float* __restrict__ A2,
              const float* __restrict__ Wl, const float* __restrict__ Wr,
              const float* __restrict__ bias, float* __restrict__ out) {
    __shared__ float wl[640], wr[640], bb[16];
    int tid = threadIdx.x;
    for (int i = tid; i < 640; i += 256) { wl[i] = Wl[i]; wr[i] = Wr[i]; }
    if (tid < 10) bb[tid] = bias[tid];
    __syncthreads();
    int lane = tid & 63, w = tid >> 6;
    for (int node = blockIdx.x * 4 + w; node < NN; node += gridDim.x * 4) {
        float m = A1[node * 64 + lane];
        float h = A2[node * 64 + lane];
        float r = 0.f;
#pragma unroll
        for (int f = 0; f < 10; ++f) {
            float p = fmaf(m, wl[f * 64 + lane], h * wr[f * 64 + lane]);
            p += __shfl_xor(p, 32, 64);
            p += __shfl_xor(p, 16, 64);
            p += __shfl_xor(p, 8, 64);
            p += __shfl_xor(p, 4, 64);
            p += __shfl_xor(p, 2, 64);
            p += __shfl_xor(p, 1, 64);
            if (lane == f) r = p + bb[f];
        }
        if (lane < 10) out[node * 10 + lane] = r;
    }
}

// ---------------- launch ----------------

extern "C" void kernel_launch(void* const* d_in, const int* in_sizes, int n_in,
                              void* d_out, int out_size, void* d_ws, size_t ws_size,
                              hipStream_t stream) {
    const float* x   = (const float*)d_in[0];
    const int*   ei  = (const int*)d_in[1];
    const float* Wl1 = (const float*)d_in[2];
    const float* Wr1 = (const float*)d_in[3];
    const float* b1  = (const float*)d_in[4];
    const float* g1  = (const float*)d_in[5];
    const float* be1 = (const float*)d_in[6];
    const float* Wl2 = (const float*)d_in[7];
    const float* Wr2 = (const float*)d_in[8];
    const float* b2  = (const float*)d_in[9];
    const float* g2  = (const float*)d_in[10];
    const float* be2 = (const float*)d_in[11];
    const float* Wl3 = (const float*)d_in[12];
    const float* Wr3 = (const float*)d_in[13];
    const float* b3  = (const float*)d_in[14];
    float* out = (float*)d_out;

    char* w = (char*)d_ws;
    auto alloc = [&](size_t bytes) -> void* {
        void* p = (void*)w;
        w += (bytes + 255) & ~(size_t)255;
        return p;
    };
    int*   deg    = (int*)alloc((size_t)NN * 4);
    int*   rs     = (int*)alloc((size_t)(NN + 1) * 4);
    int*   bsum   = (int*)alloc(512 * 4);
    int*   gcur   = (int*)alloc(256 * 4);
    int*   esrc   = (int*)alloc((size_t)EE * 4);
    float* mean   = (float*)alloc((size_t)NN * 64 * 4);
    float* h1     = (float*)alloc((size_t)NN * 64 * 4);
    float* stats  = (float*)alloc(256 * 4);  // sum1, ssq1, sum2, ssq2
    float* scsh   = (float*)alloc(256 * 4);  // scale1, shift1, scale2, shift2
    int2*  pairs  = (int2*)mean;             // 12.8 MB scratch, dead before mean is written

    hipMemsetAsync(deg, 0, (size_t)NN * 4, stream);
    hipMemsetAsync(stats, 0, 256 * 4, stream);

    k_degree<<<EE / 256, 256, 0, stream>>>(ei, deg);
    k_scan1<<<NB1, 256, 0, stream>>>(deg, rs, bsum);
    k_scan2<<<1, 512, 0, stream>>>(bsum);
    k_scan3<<<NB1, 256, 0, stream>>>(rs, bsum);
    k_initcur<<<1, 256, 0, stream>>>(rs, gcur);
    k_coarse<<<NCH, 256, 0, stream>>>(ei, gcur, pairs);
    k_fine<<<NBKT, 256, 0, stream>>>(rs, pairs, esrc);

    const int aggBlocks = (NN * 16) / 256;      // 6250
    const int sageBlocks = (NN + 63) / 64;      // 1563

    // layer 1
    k_aggregate<<<aggBlocks, 256, 0, stream>>>(x, rs, esrc, mean);
    k_sage64<<<sageBlocks, 256, 0, stream>>>(mean, x, Wl1, Wr1, b1, h1, stats + 0, stats + 64);
    k_bnfin<<<1, 64, 0, stream>>>(stats + 0, stats + 64, g1, be1, scsh + 0, scsh + 64);
    k_bnapply<<<aggBlocks, 256, 0, stream>>>(h1, scsh + 0, scsh + 64);

    // layer 2 (h2 written in place over h1)
    k_aggregate<<<aggBlocks, 256, 0, stream>>>(h1, rs, esrc, mean);
    k_sage64<<<sageBlocks, 256, 0, stream>>>(mean, h1, Wl2, Wr2, b2, h1, stats + 128, stats + 192);
    k_bnfin<<<1, 64, 0, stream>>>(stats + 128, stats + 192, g2, be2, scsh + 128, scsh + 192);
    k_bnapply<<<aggBlocks, 256, 0, stream>>>(h1, scsh + 128, scsh + 192);

    // layer 3
    k_aggregate<<<aggBlocks, 256, 0, stream>>>(h1, rs, esrc, mean);
    k_sage10<<<4096, 256, 0, stream>>>(mean, h1, Wl3, Wr3, b3, out);
}

// Round 3
// 503.946 us; speedup vs baseline: 1.3041x; 1.1523x over previous
//
#include <hip/hip_runtime.h>
#include <hip/hip_bf16.h>

#define NN 100000
#define EE 1600000
#define NB1 391    // ceil(NN/256)
#define BSZ 512    // dst-nodes per coarse bucket
#define NBKT 196   // ceil(NN/BSZ)
#define CHUNK 8192 // edges per k_coarse block
#define NCH 196    // ceil(EE/CHUNK)

// ---------------- CSR build ----------------

__global__ void k_degree(const int* __restrict__ ei, int* __restrict__ deg) {
    int e = blockIdx.x * 256 + threadIdx.x;
    if (e < EE) atomicAdd(&deg[ei[EE + e]], 1);
}

__global__ void k_scan1(const int* __restrict__ deg, int* __restrict__ rs, int* __restrict__ bsum) {
    __shared__ int s[256];
    int tid = threadIdx.x;
    int i = blockIdx.x * 256 + tid;
    int v = (i < NN) ? deg[i] : 0;
    s[tid] = v;
    __syncthreads();
    for (int off = 1; off < 256; off <<= 1) {
        int t = (tid >= off) ? s[tid - off] : 0;
        __syncthreads();
        if (tid >= off) s[tid] += t;
        __syncthreads();
    }
    if (i < NN) rs[i] = s[tid] - v;
    if (tid == 255) bsum[blockIdx.x] = s[255];
}

__global__ void k_scan2(int* __restrict__ bsum) {
    __shared__ int s[512];
    int tid = threadIdx.x;
    int v = (tid < NB1) ? bsum[tid] : 0;
    s[tid] = v;
    __syncthreads();
    for (int off = 1; off < 512; off <<= 1) {
        int t = (tid >= off) ? s[tid - off] : 0;
        __syncthreads();
        if (tid >= off) s[tid] += t;
        __syncthreads();
    }
    if (tid < NB1) bsum[tid] = s[tid] - v;
}

__global__ void k_scan3(int* __restrict__ rs, const int* __restrict__ bsum) {
    int i = blockIdx.x * 256 + threadIdx.x;
    if (i < NN) rs[i] += bsum[blockIdx.x];
    if (i == 0) rs[NN] = EE;
}

__global__ void k_initcur(const int* __restrict__ rs, int* __restrict__ gcur) {
    int b = threadIdx.x;
    if (b < NBKT) gcur[b] = rs[b * BSZ];
}

__global__ __launch_bounds__(256)
void k_coarse(const int* __restrict__ ei, int* __restrict__ gcur, int2* __restrict__ pairs) {
    __shared__ int hist[NBKT];
    __shared__ int base[NBKT];
    __shared__ int curs[NBKT];
    int tid = threadIdx.x;
    int e0 = blockIdx.x * CHUNK;
    int e1 = e0 + CHUNK; if (e1 > EE) e1 = EE;
    for (int i = tid; i < NBKT; i += 256) hist[i] = 0;
    __syncthreads();
    for (int e = e0 + tid; e < e1; e += 256)
        atomicAdd(&hist[ei[EE + e] >> 9], 1);
    __syncthreads();
    for (int i = tid; i < NBKT; i += 256) {
        base[i] = atomicAdd(&gcur[i], hist[i]);
        curs[i] = 0;
    }
    __syncthreads();
    for (int e = e0 + tid; e < e1; e += 256) {
        int src = ei[e];
        int dst = ei[EE + e];
        int b = dst >> 9;
        int off = atomicAdd(&curs[b], 1);
        pairs[base[b] + off] = make_int2(src, dst);
    }
}

__global__ __launch_bounds__(256)
void k_fine(const int* __restrict__ rs, const int2* __restrict__ pairs, int* __restrict__ esrc) {
    __shared__ int cur[BSZ];
    int b = blockIdx.x;
    int n0 = b * BSZ;
    int n1 = n0 + BSZ; if (n1 > NN) n1 = NN;
    int tid = threadIdx.x;
    for (int i = tid; i < n1 - n0; i += 256) cur[i] = rs[n0 + i];
    __syncthreads();
    int e0 = rs[n0], e1 = rs[n1];
    for (int e = e0 + tid; e < e1; e += 256) {
        int2 p = pairs[e];
        int pos = atomicAdd(&cur[p.y - n0], 1);
        esrc[pos] = p.x;
    }
}

// ---------------- aggregation (64-dim): mean over incoming neighbors ----------------
// 16 threads per node, float4 per thread. Optional fused BN+ReLU on gathered rows.
__global__ void k_aggregate(const float* __restrict__ x, const int* __restrict__ rs,
                            const int* __restrict__ esrc, float* __restrict__ mean,
                            const float* __restrict__ sc, const float* __restrict__ sh) {
    int gid = blockIdx.x * 256 + threadIdx.x;
    int node = gid >> 4;
    if (node >= NN) return;
    int c = gid & 15;
    int s0 = rs[node], s1 = rs[node + 1];
    const float4* x4 = (const float4*)x;
    float4 sc4 = make_float4(1.f, 1.f, 1.f, 1.f);
    float4 sh4 = make_float4(0.f, 0.f, 0.f, 0.f);
    bool bn = (sc != nullptr);
    if (bn) { sc4 = ((const float4*)sc)[c]; sh4 = ((const float4*)sh)[c]; }
    float4 acc = make_float4(0.f, 0.f, 0.f, 0.f);
    if (bn) {
        for (int p = s0; p < s1; ++p) {
            float4 v = x4[esrc[p] * 16 + c];
            acc.x += fmaxf(fmaf(v.x, sc4.x, sh4.x), 0.f);
            acc.y += fmaxf(fmaf(v.y, sc4.y, sh4.y), 0.f);
            acc.z += fmaxf(fmaf(v.z, sc4.z, sh4.z), 0.f);
            acc.w += fmaxf(fmaf(v.w, sc4.w, sh4.w), 0.f);
        }
    } else {
        int p = s0;
        for (; p + 2 <= s1; p += 2) {
            int sa = esrc[p], sb = esrc[p + 1];
            float4 va = x4[sa * 16 + c];
            float4 vb = x4[sb * 16 + c];
            acc.x += va.x + vb.x; acc.y += va.y + vb.y;
            acc.z += va.z + vb.z; acc.w += va.w + vb.w;
        }
        if (p < s1) {
            float4 va = x4[esrc[p] * 16 + c];
            acc.x += va.x; acc.y += va.y; acc.z += va.z; acc.w += va.w;
        }
    }
    int cnt = s1 - s0; if (cnt < 1) cnt = 1;
    float inv = 1.0f / (float)cnt;
    acc.x *= inv; acc.y *= inv; acc.z *= inv; acc.w *= inv;
    ((float4*)mean)[node * 16 + c] = acc;
}

// ---------------- SAGE layer (D_H=64): GEMM K=128 + bias + L2-norm + BN stats ----------------
// Optional fused BN+ReLU applied to A2 rows during staging (layer 2).
__global__ __launch_bounds__(256, 2)
void k_sage64(const float* __restrict__ A1,   // mean  (N,64)
              const float* A2,                // x / h-raw (N,64) -- may alias out
              const float* __restrict__ Wl, const float* __restrict__ Wr,
              const float* __restrict__ bias,
              float* out,                     // (N,64) -- may alias A2
              float* __restrict__ sumf, float* __restrict__ ssqf,
              const float* __restrict__ sc, const float* __restrict__ sh) {
    __shared__ float Alds[128 * 64];
    __shared__ float Wlds[128 * 64];
    const int tid = threadIdx.x;
    const int base = blockIdx.x * 64;

    {
        const float4* Wl4 = (const float4*)Wl;
        const float4* Wr4 = (const float4*)Wr;
#pragma unroll
        for (int i = 0; i < 8; ++i) {
            int idx = i * 256 + tid;
            int f = idx & 63, c = idx >> 6;
            float4 w = (c < 16) ? Wl4[f * 16 + c] : Wr4[f * 16 + (c - 16)];
            int k0 = c * 4;
            Wlds[(k0 + 0) * 64 + f] = w.x;
            Wlds[(k0 + 1) * 64 + f] = w.y;
            Wlds[(k0 + 2) * 64 + f] = w.z;
            Wlds[(k0 + 3) * 64 + f] = w.w;
        }
    }
    {
        const float4* A14 = (const float4*)A1;
        const float4* A24 = (const float4*)A2;
#pragma unroll
        for (int i = 0; i < 8; ++i) {
            int idx = i * 256 + tid;
            int node = idx & 63, c = idx >> 6;
            int gn = base + node; if (gn > NN - 1) gn = NN - 1;
            float4 a;
            if (c < 16) {
                a = A14[gn * 16 + c];
            } else {
                a = A24[gn * 16 + (c - 16)];
                if (sc) {
                    float4 s4 = ((const float4*)sc)[c - 16];
                    float4 h4 = ((const float4*)sh)[c - 16];
                    a.x = fmaxf(fmaf(a.x, s4.x, h4.x), 0.f);
                    a.y = fmaxf(fmaf(a.y, s4.y, h4.y), 0.f);
                    a.z = fmaxf(fmaf(a.z, s4.z, h4.z), 0.f);
                    a.w = fmaxf(fmaf(a.w, s4.w, h4.w), 0.f);
                }
            }
            int k0 = c * 4;
            Alds[(k0 + 0) * 64 + node] = a.x;
            Alds[(k0 + 1) * 64 + node] = a.y;
            Alds[(k0 + 2) * 64 + node] = a.z;
            Alds[(k0 + 3) * 64 + node] = a.w;
        }
    }
    __syncthreads();

    const int fg = tid & 15;
    const int ng = tid >> 4;

    float acc[4][4] = {};
#pragma unroll 8
    for (int k = 0; k < 128; ++k) {
        const float4 a = *(const float4*)(Alds + k * 64 + (ng << 2));
        const float4 w = *(const float4*)(Wlds + k * 64 + (fg << 2));
        const float av[4] = {a.x, a.y, a.z, a.w};
        const float wv[4] = {w.x, w.y, w.z, w.w};
#pragma unroll
        for (int i = 0; i < 4; ++i)
#pragma unroll
            for (int j = 0; j < 4; ++j)
                acc[i][j] = fmaf(av[i], wv[j], acc[i][j]);
    }

    const float4 b4 = ((const float4*)bias)[fg];
    float ss[4];
#pragma unroll
    for (int i = 0; i < 4; ++i) {
        acc[i][0] += b4.x; acc[i][1] += b4.y; acc[i][2] += b4.z; acc[i][3] += b4.w;
        ss[i] = acc[i][0] * acc[i][0] + acc[i][1] * acc[i][1] +
                acc[i][2] * acc[i][2] + acc[i][3] * acc[i][3];
    }
#pragma unroll
    for (int m = 1; m <= 8; m <<= 1) {
#pragma unroll
        for (int i = 0; i < 4; ++i) ss[i] += __shfl_xor(ss[i], m, 64);
    }
    float sj[4] = {0.f, 0.f, 0.f, 0.f}, qj[4] = {0.f, 0.f, 0.f, 0.f};
#pragma unroll
    for (int i = 0; i < 4; ++i) {
        float inv = 1.0f / fmaxf(sqrtf(ss[i]), 1e-12f);
        int gn = base + (ng << 2) + i;
        bool valid = (gn < NN);
        float o0 = acc[i][0] * inv, o1 = acc[i][1] * inv;
        float o2 = acc[i][2] * inv, o3 = acc[i][3] * inv;
        if (valid) {
            ((float4*)out)[gn * 16 + fg] = make_float4(o0, o1, o2, o3);
            sj[0] += o0; sj[1] += o1; sj[2] += o2; sj[3] += o3;
            qj[0] += o0 * o0; qj[1] += o1 * o1; qj[2] += o2 * o2; qj[3] += o3 * o3;
        }
    }
#pragma unroll
    for (int m = 16; m <= 32; m <<= 1) {
#pragma unroll
        for (int j = 0; j < 4; ++j) {
            sj[j] += __shfl_xor(sj[j], m, 64);
            qj[j] += __shfl_xor(qj[j], m, 64);
        }
    }
    __syncthreads();
    float* sblk = Alds;
    float* qblk = Alds + 64;
    if (tid < 128) Alds[tid] = 0.0f;
    __syncthreads();
    if ((tid & 63) < 16) {
#pragma unroll
        for (int j = 0; j < 4; ++j) {
            atomicAdd(&sblk[fg * 4 + j], sj[j]);
            atomicAdd(&qblk[fg * 4 + j], qj[j]);
        }
    }
    __syncthreads();
    if (tid < 64) {
        atomicAdd(&sumf[tid], sblk[tid]);
        atomicAdd(&ssqf[tid], qblk[tid]);
    }
}

// ---------------- BN finalize ----------------

__global__ void k_bnfin(const float* __restrict__ sumf, const float* __restrict__ ssqf,
                        const float* __restrict__ g, const float* __restrict__ be,
                        float* __restrict__ scale, float* __restrict__ shift) {
    int f = threadIdx.x;  // 64
    float mu = sumf[f] / (float)NN;
    float var = ssqf[f] / (float)NN - mu * mu;
    var = fmaxf(var, 0.0f);
    float sc = g[f] / sqrtf(var + 1e-5f);
    scale[f] = sc;
    shift[f] = be[f] - mu * sc;
}

// ---------------- layer-3 projection: z = relu(bn2(h2raw)) @ [Wl3;Wr3]^T ----------------
// tile = 128 nodes x 32 padded features (f 0..15 -> zl[0..9], f 16..31 -> zr[0..9]+b3).
// 256 threads, 4x4 micro-tile: fg = tid&7 (8 feature quads), ng = tid>>3 (32 node quads).
__global__ __launch_bounds__(256)
void k_project(const float* __restrict__ h,     // h2 raw (N,64)
               const float* __restrict__ sc, const float* __restrict__ sh,
               const float* __restrict__ Wl, const float* __restrict__ Wr,
               const float* __restrict__ bias,
               float* __restrict__ zl, float* __restrict__ zr) {  // (N,12) each, padded
    __shared__ float Alds[64 * 128];
    __shared__ float Wlds[64 * 32];
    const int tid = threadIdx.x;
    const int base = blockIdx.x * 128;

    // stage weights [k][f]: f<16 -> Wl row f (0 if f>=10), f>=16 -> Wr row f-16 (0 if >=10)
#pragma unroll
    for (int i = 0; i < 8; ++i) {
        int idx = i * 256 + tid;
        int f = idx & 31, k = idx >> 5;
        float v = 0.0f;
        if (f < 16) { if (f < 10) v = Wl[f * 64 + k]; }
        else        { if (f - 16 < 10) v = Wr[(f - 16) * 64 + k]; }
        Wlds[k * 32 + f] = v;
    }
    // stage A [k][node] with fused BN+ReLU
    {
        const float4* h4 = (const float4*)h;
        const float4* sc4p = (const float4*)sc;
        const float4* sh4p = (const float4*)sh;
#pragma unroll
        for (int i = 0; i < 8; ++i) {
            int idx = i * 256 + tid;
            int node = idx & 127, c = idx >> 7;
            int gn = base + node; if (gn > NN - 1) gn = NN - 1;
            float4 a = h4[gn * 16 + c];
            float4 s4 = sc4p[c], t4 = sh4p[c];
            a.x = fmaxf(fmaf(a.x, s4.x, t4.x), 0.f);
            a.y = fmaxf(fmaf(a.y, s4.y, t4.y), 0.f);
            a.z = fmaxf(fmaf(a.z, s4.z, t4.z), 0.f);
            a.w = fmaxf(fmaf(a.w, s4.w, t4.w), 0.f);
            int k0 = c * 4;
            Alds[(k0 + 0) * 128 + node] = a.x;
            Alds[(k0 + 1) * 128 + node] = a.y;
            Alds[(k0 + 2) * 128 + node] = a.z;
            Alds[(k0 + 3) * 128 + node] = a.w;
        }
    }
    __syncthreads();

    const int fg = tid & 7;     // feature quad: f = fg*4..fg*4+3
    const int ng = tid >> 3;    // node quad:    n = ng*4..ng*4+3

    float acc[4][4] = {};
#pragma unroll 4
    for (int k = 0; k < 64; ++k) {
        const float4 a = *(const float4*)(Alds + k * 128 + (ng << 2));
        const float4 w = *(const float4*)(Wlds + k * 32 + (fg << 2));
        const float av[4] = {a.x, a.y, a.z, a.w};
        const float wv[4] = {w.x, w.y, w.z, w.w};
#pragma unroll
        for (int i = 0; i < 4; ++i)
#pragma unroll
            for (int j = 0; j < 4; ++j)
                acc[i][j] = fmaf(av[i], wv[j], acc[i][j]);
    }

    // epilogue: fg 0..2 -> zl quads 0..2; fg 4..6 -> zr quads 0..2 (+bias); fg 3,7 dead
    if (fg == 3 || fg == 7) return;
    float4* dst = (fg < 4) ? (float4*)zl : (float4*)zr;
    int fq = (fg < 4) ? fg : fg - 4;
    float bx = 0.f, by = 0.f, bz = 0.f, bw = 0.f;
    if (fg >= 4) {
        int f0 = fq * 4;
        bx = (f0 + 0 < 10) ? bias[f0 + 0] : 0.f;
        by = (f0 + 1 < 10) ? bias[f0 + 1] : 0.f;
        bz = (f0 + 2 < 10) ? bias[f0 + 2] : 0.f;
        bw = (f0 + 3 < 10) ? bias[f0 + 3] : 0.f;
    }
#pragma unroll
    for (int i = 0; i < 4; ++i) {
        int gn = base + (ng << 2) + i;
        if (gn < NN)
            dst[gn * 3 + fq] = make_float4(acc[i][0] + bx, acc[i][1] + by,
                                           acc[i][2] + bz, acc[i][3] + bw);
    }
}

// ---------------- layer-3 aggregation (10-dim): out = mean(zl[src]) + zr ----------------
// 3 threads per node, one float4 quad each (rows padded to 12 floats).
__global__ __launch_bounds__(256)
void k_agg10(const int* __restrict__ rs, const int* __restrict__ esrc,
             const float* __restrict__ zl, const float* __restrict__ zr,
             float* __restrict__ out) {
    int gid = blockIdx.x * 256 + threadIdx.x;
    unsigned node = (unsigned)gid / 3u;
    int j = gid - (int)node * 3;
    if (node >= NN) return;
    int s0 = rs[node], s1 = rs[node + 1];
    const float4* zl4 = (const float4*)zl;
    float4 acc = make_float4(0.f, 0.f, 0.f, 0.f);
    for (int p = s0; p < s1; ++p) {
        float4 v = zl4[esrc[p] * 3 + j];
        acc.x += v.x; acc.y += v.y; acc.z += v.z; acc.w += v.w;
    }
    int cnt = s1 - s0; if (cnt < 1) cnt = 1;
    float inv = 1.0f / (float)cnt;
    float4 r = ((const float4*)zr)[node * 3 + j];
    r.x = fmaf(acc.x, inv, r.x); r.y = fmaf(acc.y, inv, r.y);
    r.z = fmaf(acc.z, inv, r.z); r.w = fmaf(acc.w, inv, r.w);
    float2* o2 = (float2*)(out + (size_t)node * 10);
    if (j < 2) {
        o2[j * 2 + 0] = make_float2(r.x, r.y);
        o2[j * 2 + 1] = make_float2(r.z, r.w);
    } else {
        o2[4] = make_float2(r.x, r.y);   // f8, f9; r.z/r.w are pad
    }
}

// ---------------- launch ----------------

extern "C" void kernel_launch(void* const* d_in, const int* in_sizes, int n_in,
                              void* d_out, int out_size, void* d_ws, size_t ws_size,
                              hipStream_t stream) {
    const float* x   = (const float*)d_in[0];
    const int*   ei  = (const int*)d_in[1];
    const float* Wl1 = (const float*)d_in[2];
    const float* Wr1 = (const float*)d_in[3];
    const float* b1  = (const float*)d_in[4];
    const float* g1  = (const float*)d_in[5];
    const float* be1 = (const float*)d_in[6];
    const float* Wl2 = (const float*)d_in[7];
    const float* Wr2 = (const float*)d_in[8];
    const float* b2  = (const float*)d_in[9];
    const float* g2  = (const float*)d_in[10];
    const float* be2 = (const float*)d_in[11];
    const float* Wl3 = (const float*)d_in[12];
    const float* Wr3 = (const float*)d_in[13];
    const float* b3  = (const float*)d_in[14];
    float* out = (float*)d_out;

    char* w = (char*)d_ws;
    auto alloc = [&](size_t bytes) -> void* {
        void* p = (void*)w;
        w += (bytes + 255) & ~(size_t)255;
        return p;
    };
    int*   deg    = (int*)alloc((size_t)NN * 4);
    int*   rs     = (int*)alloc((size_t)(NN + 1) * 4);
    int*   bsum   = (int*)alloc(512 * 4);
    int*   gcur   = (int*)alloc(256 * 4);
    int*   esrc   = (int*)alloc((size_t)EE * 4);
    float* mean   = (float*)alloc((size_t)NN * 64 * 4);
    float* h1     = (float*)alloc((size_t)NN * 64 * 4);
    float* stats  = (float*)alloc(256 * 4);  // sum1, ssq1, sum2, ssq2
    float* scsh   = (float*)alloc(256 * 4);  // scale1, shift1, scale2, shift2
    int2*  pairs  = (int2*)mean;             // aliases mean (dead before mean written)
    float* zl     = mean;                    // aliases mean (dead after layer-2 sage64)
    float* zr     = mean + (size_t)NN * 12;

    hipMemsetAsync(deg, 0, (size_t)NN * 4, stream);
    hipMemsetAsync(stats, 0, 256 * 4, stream);

    k_degree<<<EE / 256, 256, 0, stream>>>(ei, deg);
    k_scan1<<<NB1, 256, 0, stream>>>(deg, rs, bsum);
    k_scan2<<<1, 512, 0, stream>>>(bsum);
    k_scan3<<<NB1, 256, 0, stream>>>(rs, bsum);
    k_initcur<<<1, 256, 0, stream>>>(rs, gcur);
    k_coarse<<<NCH, 256, 0, stream>>>(ei, gcur, pairs);
    k_fine<<<NBKT, 256, 0, stream>>>(rs, pairs, esrc);

    const int aggBlocks  = (NN * 16) / 256;      // 6250
    const int sageBlocks = (NN + 63) / 64;       // 1563
    const int projBlocks = (NN + 127) / 128;     // 782
    const int a10Blocks  = (NN * 3 + 255) / 256; // 1172

    // layer 1
    k_aggregate<<<aggBlocks, 256, 0, stream>>>(x, rs, esrc, mean, nullptr, nullptr);
    k_sage64<<<sageBlocks, 256, 0, stream>>>(mean, x, Wl1, Wr1, b1, h1,
                                             stats + 0, stats + 64, nullptr, nullptr);
    k_bnfin<<<1, 64, 0, stream>>>(stats + 0, stats + 64, g1, be1, scsh + 0, scsh + 64);

    // layer 2: BN1+ReLU fused into aggregate and A2 staging; h2raw overwrites h1
    k_aggregate<<<aggBlocks, 256, 0, stream>>>(h1, rs, esrc, mean, scsh + 0, scsh + 64);
    k_sage64<<<sageBlocks, 256, 0, stream>>>(mean, h1, Wl2, Wr2, b2, h1,
                                             stats + 128, stats + 192, scsh + 0, scsh + 64);
    k_bnfin<<<1, 64, 0, stream>>>(stats + 128, stats + 192, g2, be2, scsh + 128, scsh + 192);

    // layer 3: project (BN2+ReLU fused) then 10-dim aggregate
    k_project<<<projBlocks, 256, 0, stream>>>(h1, scsh + 128, scsh + 192,
                                              Wl3, Wr3, b3, zl, zr);
    k_agg10<<<a10Blocks, 256, 0, stream>>>(rs, esrc, zl, zr, out);
}

// Round 4
// 499.969 us; speedup vs baseline: 1.3144x; 1.0080x over previous
//
#include <hip/hip_runtime.h>
#include <hip/hip_bf16.h>

#define NN 100000
#define EE 1600000
#define NB1 391    // ceil(NN/256)
#define BSZ 512    // dst-nodes per coarse bucket
#define NBKT 196   // ceil(NN/BSZ)
#define CHUNK 8192 // edges per k_coarse block
#define NCH 196    // ceil(EE/CHUNK)

// ---------------- CSR build ----------------

__global__ void k_degree(const int* __restrict__ ei, int* __restrict__ deg) {
    int e = blockIdx.x * 256 + threadIdx.x;
    if (e < EE) atomicAdd(&deg[ei[EE + e]], 1);
}

__global__ void k_scan1(const int* __restrict__ deg, int* __restrict__ rs, int* __restrict__ bsum) {
    __shared__ int s[256];
    int tid = threadIdx.x;
    int i = blockIdx.x * 256 + tid;
    int v = (i < NN) ? deg[i] : 0;
    s[tid] = v;
    __syncthreads();
    for (int off = 1; off < 256; off <<= 1) {
        int t = (tid >= off) ? s[tid - off] : 0;
        __syncthreads();
        if (tid >= off) s[tid] += t;
        __syncthreads();
    }
    if (i < NN) rs[i] = s[tid] - v;
    if (tid == 255) bsum[blockIdx.x] = s[255];
}

__global__ void k_scan2(int* __restrict__ bsum) {
    __shared__ int s[512];
    int tid = threadIdx.x;
    int v = (tid < NB1) ? bsum[tid] : 0;
    s[tid] = v;
    __syncthreads();
    for (int off = 1; off < 512; off <<= 1) {
        int t = (tid >= off) ? s[tid - off] : 0;
        __syncthreads();
        if (tid >= off) s[tid] += t;
        __syncthreads();
    }
    if (tid < NB1) bsum[tid] = s[tid] - v;
}

__global__ void k_scan3(int* __restrict__ rs, const int* __restrict__ bsum) {
    int i = blockIdx.x * 256 + threadIdx.x;
    if (i < NN) rs[i] += bsum[blockIdx.x];
    if (i == 0) rs[NN] = EE;
}

__global__ void k_initcur(const int* __restrict__ rs, int* __restrict__ gcur) {
    int b = threadIdx.x;
    if (b < NBKT) gcur[b] = rs[b * BSZ];
}

__global__ __launch_bounds__(256)
void k_coarse(const int* __restrict__ ei, int* __restrict__ gcur, int2* __restrict__ pairs) {
    __shared__ int hist[NBKT];
    __shared__ int base[NBKT];
    __shared__ int curs[NBKT];
    int tid = threadIdx.x;
    int e0 = blockIdx.x * CHUNK;
    int e1 = e0 + CHUNK; if (e1 > EE) e1 = EE;
    for (int i = tid; i < NBKT; i += 256) hist[i] = 0;
    __syncthreads();
    for (int e = e0 + tid; e < e1; e += 256)
        atomicAdd(&hist[ei[EE + e] >> 9], 1);
    __syncthreads();
    for (int i = tid; i < NBKT; i += 256) {
        base[i] = atomicAdd(&gcur[i], hist[i]);
        curs[i] = 0;
    }
    __syncthreads();
    for (int e = e0 + tid; e < e1; e += 256) {
        int src = ei[e];
        int dst = ei[EE + e];
        int b = dst >> 9;
        int off = atomicAdd(&curs[b], 1);
        pairs[base[b] + off] = make_int2(src, dst);
    }
}

__global__ __launch_bounds__(256)
void k_fine(const int* __restrict__ rs, const int2* __restrict__ pairs, int* __restrict__ esrc) {
    __shared__ int cur[BSZ];
    int b = blockIdx.x;
    int n0 = b * BSZ;
    int n1 = n0 + BSZ; if (n1 > NN) n1 = NN;
    int tid = threadIdx.x;
    for (int i = tid; i < n1 - n0; i += 256) cur[i] = rs[n0 + i];
    __syncthreads();
    int e0 = rs[n0], e1 = rs[n1];
    for (int e = e0 + tid; e < e1; e += 256) {
        int2 p = pairs[e];
        int pos = atomicAdd(&cur[p.y - n0], 1);
        esrc[pos] = p.x;
    }
}

// ---------------- aggregation (64-dim): mean over incoming neighbors ----------------
// One wave per node: 16 feature-lanes x 4 neighbor slots -> 4 independent
// gather streams per node (4x memory-level parallelism vs 1 chain).
__global__ __launch_bounds__(256)
void k_aggregate(const float* __restrict__ x, const int* __restrict__ rs,
                 const int* __restrict__ esrc, float* __restrict__ mean,
                 const float* __restrict__ sc, const float* __restrict__ sh) {
    int gid = blockIdx.x * 256 + threadIdx.x;
    int node = gid >> 6;
    if (node >= NN) return;
    int lane = threadIdx.x & 63;
    int c = lane & 15;        // feature quad
    int slot = lane >> 4;     // neighbor slot 0..3
    int s0 = rs[node], s1 = rs[node + 1];
    const float4* x4 = (const float4*)x;
    float4 acc = make_float4(0.f, 0.f, 0.f, 0.f);
    if (sc) {
        float4 sc4 = ((const float4*)sc)[c];
        float4 sh4 = ((const float4*)sh)[c];
        for (int p = s0 + slot; p < s1; p += 4) {
            float4 v = x4[esrc[p] * 16 + c];
            acc.x += fmaxf(fmaf(v.x, sc4.x, sh4.x), 0.f);
            acc.y += fmaxf(fmaf(v.y, sc4.y, sh4.y), 0.f);
            acc.z += fmaxf(fmaf(v.z, sc4.z, sh4.z), 0.f);
            acc.w += fmaxf(fmaf(v.w, sc4.w, sh4.w), 0.f);
        }
    } else {
        for (int p = s0 + slot; p < s1; p += 4) {
            float4 v = x4[esrc[p] * 16 + c];
            acc.x += v.x; acc.y += v.y; acc.z += v.z; acc.w += v.w;
        }
    }
    // reduce across the 4 slots (lanes xor 16, 32)
    acc.x += __shfl_xor(acc.x, 16, 64); acc.y += __shfl_xor(acc.y, 16, 64);
    acc.z += __shfl_xor(acc.z, 16, 64); acc.w += __shfl_xor(acc.w, 16, 64);
    acc.x += __shfl_xor(acc.x, 32, 64); acc.y += __shfl_xor(acc.y, 32, 64);
    acc.z += __shfl_xor(acc.z, 32, 64); acc.w += __shfl_xor(acc.w, 32, 64);
    if (slot == 0) {
        int cnt = s1 - s0; if (cnt < 1) cnt = 1;
        float inv = 1.0f / (float)cnt;
        ((float4*)mean)[node * 16 + c] =
            make_float4(acc.x * inv, acc.y * inv, acc.z * inv, acc.w * inv);
    }
}

// ---------------- SAGE layer (D_H=64): split-K GEMM + bias + L2-norm + BN stats ----------------
// K=128 processed as two K=64 halves (half 0: A1/Wl, half 1: A2/Wr + fused BN).
// LDS = 16+16 = 32 KB -> 4-5 blocks/CU (was 64 KB -> 2).
__global__ __launch_bounds__(256, 4)
void k_sage64(const float* __restrict__ A1,   // mean  (N,64)
              const float* A2,                // x / h-raw (N,64) -- may alias out
              const float* __restrict__ Wl, const float* __restrict__ Wr,
              const float* __restrict__ bias,
              float* out,                     // (N,64) -- may alias A2
              float* __restrict__ sumf, float* __restrict__ ssqf,
              const float* __restrict__ sc, const float* __restrict__ sh) {
    __shared__ float Alds[64 * 64];
    __shared__ float Wlds[64 * 64];
    const int tid = threadIdx.x;
    const int base = blockIdx.x * 64;
    const int fg = tid & 15;    // feature quad
    const int ng = tid >> 4;    // node quad

    float acc[4][4] = {};

    for (int kh = 0; kh < 2; ++kh) {
        const float4* W4 = (const float4*)(kh == 0 ? Wl : Wr);
        const float4* A4 = (const float4*)(kh == 0 ? A1 : A2);
        if (kh) __syncthreads();   // previous compute done before overwrite
        // stage W half: Wlds[k][f] = W[f][k], lanes vary f fastest (conflict-free)
#pragma unroll
        for (int i = 0; i < 4; ++i) {
            int idx = i * 256 + tid;
            int f = idx & 63, c = idx >> 6;          // c in [0,16)
            float4 w = W4[f * 16 + c];
            int k0 = c * 4;
            Wlds[(k0 + 0) * 64 + f] = w.x;
            Wlds[(k0 + 1) * 64 + f] = w.y;
            Wlds[(k0 + 2) * 64 + f] = w.z;
            Wlds[(k0 + 3) * 64 + f] = w.w;
        }
        // stage A half: Alds[k][node], fused BN+ReLU on half 1 if sc given
#pragma unroll
        for (int i = 0; i < 4; ++i) {
            int idx = i * 256 + tid;
            int node = idx & 63, c = idx >> 6;
            int gn = base + node; if (gn > NN - 1) gn = NN - 1;
            float4 a = A4[gn * 16 + c];
            if (kh && sc) {
                float4 s4 = ((const float4*)sc)[c];
                float4 h4 = ((const float4*)sh)[c];
                a.x = fmaxf(fmaf(a.x, s4.x, h4.x), 0.f);
                a.y = fmaxf(fmaf(a.y, s4.y, h4.y), 0.f);
                a.z = fmaxf(fmaf(a.z, s4.z, h4.z), 0.f);
                a.w = fmaxf(fmaf(a.w, s4.w, h4.w), 0.f);
            }
            int k0 = c * 4;
            Alds[(k0 + 0) * 64 + node] = a.x;
            Alds[(k0 + 1) * 64 + node] = a.y;
            Alds[(k0 + 2) * 64 + node] = a.z;
            Alds[(k0 + 3) * 64 + node] = a.w;
        }
        __syncthreads();
#pragma unroll 8
        for (int k = 0; k < 64; ++k) {
            const float4 a = *(const float4*)(Alds + k * 64 + (ng << 2));
            const float4 w = *(const float4*)(Wlds + k * 64 + (fg << 2));
            const float av[4] = {a.x, a.y, a.z, a.w};
            const float wv[4] = {w.x, w.y, w.z, w.w};
#pragma unroll
            for (int i = 0; i < 4; ++i)
#pragma unroll
                for (int j = 0; j < 4; ++j)
                    acc[i][j] = fmaf(av[i], wv[j], acc[i][j]);
        }
    }

    // epilogue: bias, row L2-norm, write, BN stat partials
    const float4 b4 = ((const float4*)bias)[fg];
    float ss[4];
#pragma unroll
    for (int i = 0; i < 4; ++i) {
        acc[i][0] += b4.x; acc[i][1] += b4.y; acc[i][2] += b4.z; acc[i][3] += b4.w;
        ss[i] = acc[i][0] * acc[i][0] + acc[i][1] * acc[i][1] +
                acc[i][2] * acc[i][2] + acc[i][3] * acc[i][3];
    }
#pragma unroll
    for (int m = 1; m <= 8; m <<= 1) {
#pragma unroll
        for (int i = 0; i < 4; ++i) ss[i] += __shfl_xor(ss[i], m, 64);
    }
    float sj[4] = {0.f, 0.f, 0.f, 0.f}, qj[4] = {0.f, 0.f, 0.f, 0.f};
#pragma unroll
    for (int i = 0; i < 4; ++i) {
        float inv = 1.0f / fmaxf(sqrtf(ss[i]), 1e-12f);
        int gn = base + (ng << 2) + i;
        bool valid = (gn < NN);
        float o0 = acc[i][0] * inv, o1 = acc[i][1] * inv;
        float o2 = acc[i][2] * inv, o3 = acc[i][3] * inv;
        if (valid) {
            ((float4*)out)[gn * 16 + fg] = make_float4(o0, o1, o2, o3);
            sj[0] += o0; sj[1] += o1; sj[2] += o2; sj[3] += o3;
            qj[0] += o0 * o0; qj[1] += o1 * o1; qj[2] += o2 * o2; qj[3] += o3 * o3;
        }
    }
#pragma unroll
    for (int m = 16; m <= 32; m <<= 1) {
#pragma unroll
        for (int j = 0; j < 4; ++j) {
            sj[j] += __shfl_xor(sj[j], m, 64);
            qj[j] += __shfl_xor(qj[j], m, 64);
        }
    }
    __syncthreads();
    float* sblk = Alds;
    float* qblk = Alds + 64;
    if (tid < 128) Alds[tid] = 0.0f;
    __syncthreads();
    if ((tid & 63) < 16) {
#pragma unroll
        for (int j = 0; j < 4; ++j) {
            atomicAdd(&sblk[fg * 4 + j], sj[j]);
            atomicAdd(&qblk[fg * 4 + j], qj[j]);
        }
    }
    __syncthreads();
    if (tid < 64) {
        atomicAdd(&sumf[tid], sblk[tid]);
        atomicAdd(&ssqf[tid], qblk[tid]);
    }
}

// ---------------- BN finalize ----------------

__global__ void k_bnfin(const float* __restrict__ sumf, const float* __restrict__ ssqf,
                        const float* __restrict__ g, const float* __restrict__ be,
                        float* __restrict__ scale, float* __restrict__ shift) {
    int f = threadIdx.x;  // 64
    float mu = sumf[f] / (float)NN;
    float var = ssqf[f] / (float)NN - mu * mu;
    var = fmaxf(var, 0.0f);
    float sc = g[f] / sqrtf(var + 1e-5f);
    scale[f] = sc;
    shift[f] = be[f] - mu * sc;
}

// ---------------- layer-3 projection: z = relu(bn2(h2raw)) @ [Wl3;Wr3]^T ----------------
__global__ __launch_bounds__(256)
void k_project(const float* __restrict__ h,     // h2 raw (N,64)
               const float* __restrict__ sc, const float* __restrict__ sh,
               const float* __restrict__ Wl, const float* __restrict__ Wr,
               const float* __restrict__ bias,
               float* __restrict__ zl, float* __restrict__ zr) {  // (N,12) each, padded
    __shared__ float Alds[64 * 128];
    __shared__ float Wlds[64 * 32];
    const int tid = threadIdx.x;
    const int base = blockIdx.x * 128;

#pragma unroll
    for (int i = 0; i < 8; ++i) {
        int idx = i * 256 + tid;
        int f = idx & 31, k = idx >> 5;
        float v = 0.0f;
        if (f < 16) { if (f < 10) v = Wl[f * 64 + k]; }
        else        { if (f - 16 < 10) v = Wr[(f - 16) * 64 + k]; }
        Wlds[k * 32 + f] = v;
    }
    {
        const float4* h4 = (const float4*)h;
        const float4* sc4p = (const float4*)sc;
        const float4* sh4p = (const float4*)sh;
#pragma unroll
        for (int i = 0; i < 8; ++i) {
            int idx = i * 256 + tid;
            int node = idx & 127, c = idx >> 7;
            int gn = base + node; if (gn > NN - 1) gn = NN - 1;
            float4 a = h4[gn * 16 + c];
            float4 s4 = sc4p[c], t4 = sh4p[c];
            a.x = fmaxf(fmaf(a.x, s4.x, t4.x), 0.f);
            a.y = fmaxf(fmaf(a.y, s4.y, t4.y), 0.f);
            a.z = fmaxf(fmaf(a.z, s4.z, t4.z), 0.f);
            a.w = fmaxf(fmaf(a.w, s4.w, t4.w), 0.f);
            int k0 = c * 4;
            Alds[(k0 + 0) * 128 + node] = a.x;
            Alds[(k0 + 1) * 128 + node] = a.y;
            Alds[(k0 + 2) * 128 + node] = a.z;
            Alds[(k0 + 3) * 128 + node] = a.w;
        }
    }
    __syncthreads();

    const int fg = tid & 7;
    const int ng = tid >> 3;

    float acc[4][4] = {};
#pragma unroll 4
    for (int k = 0; k < 64; ++k) {
        const float4 a = *(const float4*)(Alds + k * 128 + (ng << 2));
        const float4 w = *(const float4*)(Wlds + k * 32 + (fg << 2));
        const float av[4] = {a.x, a.y, a.z, a.w};
        const float wv[4] = {w.x, w.y, w.z, w.w};
#pragma unroll
        for (int i = 0; i < 4; ++i)
#pragma unroll
            for (int j = 0; j < 4; ++j)
                acc[i][j] = fmaf(av[i], wv[j], acc[i][j]);
    }

    if (fg == 3 || fg == 7) return;
    float4* dst = (fg < 4) ? (float4*)zl : (float4*)zr;
    int fq = (fg < 4) ? fg : fg - 4;
    float bx = 0.f, by = 0.f, bz = 0.f, bw = 0.f;
    if (fg >= 4) {
        int f0 = fq * 4;
        bx = (f0 + 0 < 10) ? bias[f0 + 0] : 0.f;
        by = (f0 + 1 < 10) ? bias[f0 + 1] : 0.f;
        bz = (f0 + 2 < 10) ? bias[f0 + 2] : 0.f;
        bw = (f0 + 3 < 10) ? bias[f0 + 3] : 0.f;
    }
#pragma unroll
    for (int i = 0; i < 4; ++i) {
        int gn = base + (ng << 2) + i;
        if (gn < NN)
            dst[gn * 3 + fq] = make_float4(acc[i][0] + bx, acc[i][1] + by,
                                           acc[i][2] + bz, acc[i][3] + bw);
    }
}

// ---------------- layer-3 aggregation (10-dim): out = mean(zl[src]) + zr ----------------
__global__ __launch_bounds__(256)
void k_agg10(const int* __restrict__ rs, const int* __restrict__ esrc,
             const float* __restrict__ zl, const float* __restrict__ zr,
             float* __restrict__ out) {
    int gid = blockIdx.x * 256 + threadIdx.x;
    unsigned node = (unsigned)gid / 3u;
    int j = gid - (int)node * 3;
    if (node >= NN) return;
    int s0 = rs[node], s1 = rs[node + 1];
    const float4* zl4 = (const float4*)zl;
    float4 acc = make_float4(0.f, 0.f, 0.f, 0.f);
    for (int p = s0; p < s1; ++p) {
        float4 v = zl4[esrc[p] * 3 + j];
        acc.x += v.x; acc.y += v.y; acc.z += v.z; acc.w += v.w;
    }
    int cnt = s1 - s0; if (cnt < 1) cnt = 1;
    float inv = 1.0f / (float)cnt;
    float4 r = ((const float4*)zr)[node * 3 + j];
    r.x = fmaf(acc.x, inv, r.x); r.y = fmaf(acc.y, inv, r.y);
    r.z = fmaf(acc.z, inv, r.z); r.w = fmaf(acc.w, inv, r.w);
    float2* o2 = (float2*)(out + (size_t)node * 10);
    if (j < 2) {
        o2[j * 2 + 0] = make_float2(r.x, r.y);
        o2[j * 2 + 1] = make_float2(r.z, r.w);
    } else {
        o2[4] = make_float2(r.x, r.y);
    }
}

// ---------------- launch ----------------

extern "C" void kernel_launch(void* const* d_in, const int* in_sizes, int n_in,
                              void* d_out, int out_size, void* d_ws, size_t ws_size,
                              hipStream_t stream) {
    const float* x   = (const float*)d_in[0];
    const int*   ei  = (const int*)d_in[1];
    const float* Wl1 = (const float*)d_in[2];
    const float* Wr1 = (const float*)d_in[3];
    const float* b1  = (const float*)d_in[4];
    const float* g1  = (const float*)d_in[5];
    const float* be1 = (const float*)d_in[6];
    const float* Wl2 = (const float*)d_in[7];
    const float* Wr2 = (const float*)d_in[8];
    const float* b2  = (const float*)d_in[9];
    const float* g2  = (const float*)d_in[10];
    const float* be2 = (const float*)d_in[11];
    const float* Wl3 = (const float*)d_in[12];
    const float* Wr3 = (const float*)d_in[13];
    const float* b3  = (const float*)d_in[14];
    float* out = (float*)d_out;

    char* w = (char*)d_ws;
    auto alloc = [&](size_t bytes) -> void* {
        void* p = (void*)w;
        w += (bytes + 255) & ~(size_t)255;
        return p;
    };
    int*   deg    = (int*)alloc((size_t)NN * 4);
    int*   rs     = (int*)alloc((size_t)(NN + 1) * 4);
    int*   bsum   = (int*)alloc(512 * 4);
    int*   gcur   = (int*)alloc(256 * 4);
    int*   esrc   = (int*)alloc((size_t)EE * 4);
    float* mean   = (float*)alloc((size_t)NN * 64 * 4);
    float* h1     = (float*)alloc((size_t)NN * 64 * 4);
    float* stats  = (float*)alloc(256 * 4);  // sum1, ssq1, sum2, ssq2
    float* scsh   = (float*)alloc(256 * 4);  // scale1, shift1, scale2, shift2
    int2*  pairs  = (int2*)mean;             // aliases mean (dead before mean written)
    float* zl     = mean;                    // aliases mean (dead after layer-2 sage64)
    float* zr     = mean + (size_t)NN * 12;

    hipMemsetAsync(deg, 0, (size_t)NN * 4, stream);
    hipMemsetAsync(stats, 0, 256 * 4, stream);

    k_degree<<<EE / 256, 256, 0, stream>>>(ei, deg);
    k_scan1<<<NB1, 256, 0, stream>>>(deg, rs, bsum);
    k_scan2<<<1, 512, 0, stream>>>(bsum);
    k_scan3<<<NB1, 256, 0, stream>>>(rs, bsum);
    k_initcur<<<1, 256, 0, stream>>>(rs, gcur);
    k_coarse<<<NCH, 256, 0, stream>>>(ei, gcur, pairs);
    k_fine<<<NBKT, 256, 0, stream>>>(rs, pairs, esrc);

    const int aggBlocks  = (NN * 64) / 256;      // 25000 (1 wave / node)
    const int sageBlocks = (NN + 63) / 64;       // 1563
    const int projBlocks = (NN + 127) / 128;     // 782
    const int a10Blocks  = (NN * 3 + 255) / 256; // 1172

    // layer 1
    k_aggregate<<<aggBlocks, 256, 0, stream>>>(x, rs, esrc, mean, nullptr, nullptr);
    k_sage64<<<sageBlocks, 256, 0, stream>>>(mean, x, Wl1, Wr1, b1, h1,
                                             stats + 0, stats + 64, nullptr, nullptr);
    k_bnfin<<<1, 64, 0, stream>>>(stats + 0, stats + 64, g1, be1, scsh + 0, scsh + 64);

    // layer 2: BN1+ReLU fused into aggregate and A2 staging; h2raw overwrites h1
    k_aggregate<<<aggBlocks, 256, 0, stream>>>(h1, rs, esrc, mean, scsh + 0, scsh + 64);
    k_sage64<<<sageBlocks, 256, 0, stream>>>(mean, h1, Wl2, Wr2, b2, h1,
                                             stats + 128, stats + 192, scsh + 0, scsh + 64);
    k_bnfin<<<1, 64, 0, stream>>>(stats + 128, stats + 192, g2, be2, scsh + 128, scsh + 192);

    // layer 3: project (BN2+ReLU fused) then 10-dim aggregate
    k_project<<<projBlocks, 256, 0, stream>>>(h1, scsh + 128, scsh + 192,
                                              Wl3, Wr3, b3, zl, zr);
    k_agg10<<<a10Blocks, 256, 0, stream>>>(rs, esrc, zl, zr, out);
}

// Round 5
// 412.333 us; speedup vs baseline: 1.5938x; 1.2125x over previous
//
#include <hip/hip_runtime.h>
#include <hip/hip_bf16.h>

#define NN 100000
#define EE 1600000
#define BSZ 512    // dst-nodes per coarse bucket
#define NBKT 196   // ceil(NN/BSZ)
#define CHUNK 8192 // edges per coarse chunk
#define NCH 196    // ceil(EE/CHUNK)

// ---------------- bf16 helpers ----------------
__device__ inline unsigned short bf16_of(float f) {
    __hip_bfloat16 h = __float2bfloat16(f);   // RNE
    return *reinterpret_cast<unsigned short*>(&h);
}
__device__ inline float bflo(unsigned u) { return __uint_as_float(u << 16); }
__device__ inline float bfhi(unsigned u) { return __uint_as_float(u & 0xffff0000u); }

// ---------------- CSR build (no per-node global atomics) ----------------

// coarse histogram: 196 bins, LDS-aggregated
__global__ __launch_bounds__(256)
void k_ccount(const int* __restrict__ ei, int* __restrict__ ccount) {
    __shared__ int hist[NBKT];
    int tid = threadIdx.x;
    int e0 = blockIdx.x * CHUNK;
    int e1 = e0 + CHUNK; if (e1 > EE) e1 = EE;
    for (int i = tid; i < NBKT; i += 256) hist[i] = 0;
    __syncthreads();
    for (int e = e0 + tid; e < e1; e += 256)
        atomicAdd(&hist[ei[EE + e] >> 9], 1);
    __syncthreads();
    for (int i = tid; i < NBKT; i += 256)
        if (hist[i]) atomicAdd(&ccount[i], hist[i]);
}

// scan 196 bucket sizes -> cbase (exclusive), init gcur
__global__ void k_cscan(const int* __restrict__ ccount, int* __restrict__ cbase,
                        int* __restrict__ gcur) {
    __shared__ int s[256];
    int tid = threadIdx.x;
    int v = (tid < NBKT) ? ccount[tid] : 0;
    s[tid] = v;
    __syncthreads();
    for (int off = 1; off < 256; off <<= 1) {
        int t = (tid >= off) ? s[tid - off] : 0;
        __syncthreads();
        if (tid >= off) s[tid] += t;
        __syncthreads();
    }
    if (tid < NBKT) {
        int excl = s[tid] - v;
        cbase[tid] = excl;
        gcur[tid] = excl;
    }
    if (tid == NBKT - 1) cbase[NBKT] = s[tid];   // == EE
}

__global__ __launch_bounds__(256)
void k_coarse(const int* __restrict__ ei, int* __restrict__ gcur, int2* __restrict__ pairs) {
    __shared__ int hist[NBKT];
    __shared__ int base[NBKT];
    __shared__ int curs[NBKT];
    int tid = threadIdx.x;
    int e0 = blockIdx.x * CHUNK;
    int e1 = e0 + CHUNK; if (e1 > EE) e1 = EE;
    for (int i = tid; i < NBKT; i += 256) hist[i] = 0;
    __syncthreads();
    for (int e = e0 + tid; e < e1; e += 256)
        atomicAdd(&hist[ei[EE + e] >> 9], 1);
    __syncthreads();
    for (int i = tid; i < NBKT; i += 256) {
        base[i] = atomicAdd(&gcur[i], hist[i]);
        curs[i] = 0;
    }
    __syncthreads();
    for (int e = e0 + tid; e < e1; e += 256) {
        int src = ei[e];
        int dst = ei[EE + e];
        int b = dst >> 9;
        int off = atomicAdd(&curs[b], 1);
        pairs[base[b] + off] = make_int2(src, dst);
    }
}

// fine pass: per bucket LDS degree count + LDS scan -> writes rs AND esrc.
__global__ __launch_bounds__(512)
void k_fine(const int* __restrict__ cbase, const int2* __restrict__ pairs,
            int* __restrict__ rs, int* __restrict__ esrc) {
    __shared__ int deg[BSZ];
    __shared__ int s[BSZ];
    int b = blockIdx.x;
    int n0 = b * BSZ;
    int nlocal = NN - n0; if (nlocal > BSZ) nlocal = BSZ;
    int tid = threadIdx.x;
    deg[tid] = 0;
    __syncthreads();
    int e0 = cbase[b], e1 = cbase[b + 1];
    for (int e = e0 + tid; e < e1; e += 512)
        atomicAdd(&deg[pairs[e].y - n0], 1);
    __syncthreads();
    int v = deg[tid];
    s[tid] = v;
    __syncthreads();
    for (int off = 1; off < 512; off <<= 1) {
        int t = (tid >= off) ? s[tid - off] : 0;
        __syncthreads();
        if (tid >= off) s[tid] += t;
        __syncthreads();
    }
    int excl = s[tid] - v;
    if (tid < nlocal) rs[n0 + tid] = e0 + excl;
    if (b == NBKT - 1 && tid == 0) rs[NN] = EE;
    deg[tid] = e0 + excl;   // becomes the cursor
    __syncthreads();
    for (int e = e0 + tid; e < e1; e += 512) {
        int2 p = pairs[e];
        int pos = atomicAdd(&deg[p.y - n0], 1);
        esrc[pos] = p.x;
    }
}

// ---------------- fp32 -> bf16 table conversion ----------------
__global__ void k_tobf(const float4* __restrict__ src, ushort4* __restrict__ dst) {
    int i = blockIdx.x * 256 + threadIdx.x;   // over NN*16 float4
    if (i >= NN * 16) return;
    float4 v = src[i];
    dst[i] = make_ushort4(bf16_of(v.x), bf16_of(v.y), bf16_of(v.z), bf16_of(v.w));
}

// ---------------- aggregation (64-dim) over bf16 table ----------------
// One wave per node: 8 feature-lanes (8 feats each, 16B) x 8 neighbor slots.
__global__ __launch_bounds__(256)
void k_aggbf(const unsigned short* __restrict__ xbf, const int* __restrict__ rs,
             const int* __restrict__ esrc, float* __restrict__ mean,
             const float* __restrict__ sc, const float* __restrict__ sh) {
    int gid = blockIdx.x * 256 + threadIdx.x;
    int node = gid >> 6;
    if (node >= NN) return;
    int lane = threadIdx.x & 63;
    int c = lane & 7;         // feature octet: feats c*8..c*8+7
    int slot = lane >> 3;     // neighbor slot 0..7
    int s0 = rs[node], s1 = rs[node + 1];
    const uint4* xb = (const uint4*)xbf;      // row = 8 uint4 (64 bf16)
    float a0 = 0.f, a1 = 0.f, a2 = 0.f, a3 = 0.f, a4 = 0.f, a5 = 0.f, a6 = 0.f, a7 = 0.f;
    if (sc) {
        float4 scl = ((const float4*)sc)[2 * c], sch = ((const float4*)sc)[2 * c + 1];
        float4 shl = ((const float4*)sh)[2 * c], shh = ((const float4*)sh)[2 * c + 1];
        for (int p = s0 + slot; p < s1; p += 8) {
            uint4 v = xb[esrc[p] * 8 + c];
            a0 += fmaxf(fmaf(bflo(v.x), scl.x, shl.x), 0.f);
            a1 += fmaxf(fmaf(bfhi(v.x), scl.y, shl.y), 0.f);
            a2 += fmaxf(fmaf(bflo(v.y), scl.z, shl.z), 0.f);
            a3 += fmaxf(fmaf(bfhi(v.y), scl.w, shl.w), 0.f);
            a4 += fmaxf(fmaf(bflo(v.z), sch.x, shh.x), 0.f);
            a5 += fmaxf(fmaf(bfhi(v.z), sch.y, shh.y), 0.f);
            a6 += fmaxf(fmaf(bflo(v.w), sch.z, shh.z), 0.f);
            a7 += fmaxf(fmaf(bfhi(v.w), sch.w, shh.w), 0.f);
        }
    } else {
        for (int p = s0 + slot; p < s1; p += 8) {
            uint4 v = xb[esrc[p] * 8 + c];
            a0 += bflo(v.x); a1 += bfhi(v.x);
            a2 += bflo(v.y); a3 += bfhi(v.y);
            a4 += bflo(v.z); a5 += bfhi(v.z);
            a6 += bflo(v.w); a7 += bfhi(v.w);
        }
    }
#pragma unroll
    for (int m = 8; m <= 32; m <<= 1) {
        a0 += __shfl_xor(a0, m, 64); a1 += __shfl_xor(a1, m, 64);
        a2 += __shfl_xor(a2, m, 64); a3 += __shfl_xor(a3, m, 64);
        a4 += __shfl_xor(a4, m, 64); a5 += __shfl_xor(a5, m, 64);
        a6 += __shfl_xor(a6, m, 64); a7 += __shfl_xor(a7, m, 64);
    }
    if (slot == 0) {
        int cnt = s1 - s0; if (cnt < 1) cnt = 1;
        float inv = 1.0f / (float)cnt;
        ((float4*)mean)[node * 16 + 2 * c]     = make_float4(a0 * inv, a1 * inv, a2 * inv, a3 * inv);
        ((float4*)mean)[node * 16 + 2 * c + 1] = make_float4(a4 * inv, a5 * inv, a6 * inv, a7 * inv);
    }
}

// ---------------- SAGE layer (D_H=64): split-K GEMM + bias + L2-norm + BN stats ----------------
__global__ __launch_bounds__(256, 4)
void k_sage64(const float* __restrict__ A1,   // mean  (N,64)
              const float* A2,                // x / h-raw (N,64) -- may alias out
              const float* __restrict__ Wl, const float* __restrict__ Wr,
              const float* __restrict__ bias,
              float* out,                     // (N,64)
              ushort4* __restrict__ outbf,    // optional bf16 copy of out
              float* __restrict__ sumf, float* __restrict__ ssqf,
              const float* __restrict__ sc, const float* __restrict__ sh) {
    __shared__ float Alds[64 * 64];
    __shared__ float Wlds[64 * 64];
    const int tid = threadIdx.x;
    const int base = blockIdx.x * 64;
    const int fg = tid & 15;
    const int ng = tid >> 4;

    float acc[4][4] = {};

    for (int kh = 0; kh < 2; ++kh) {
        const float4* W4 = (const float4*)(kh == 0 ? Wl : Wr);
        const float4* A4 = (const float4*)(kh == 0 ? A1 : A2);
        if (kh) __syncthreads();
#pragma unroll
        for (int i = 0; i < 4; ++i) {
            int idx = i * 256 + tid;
            int f = idx & 63, c = idx >> 6;
            float4 w = W4[f * 16 + c];
            int k0 = c * 4;
            Wlds[(k0 + 0) * 64 + f] = w.x;
            Wlds[(k0 + 1) * 64 + f] = w.y;
            Wlds[(k0 + 2) * 64 + f] = w.z;
            Wlds[(k0 + 3) * 64 + f] = w.w;
        }
#pragma unroll
        for (int i = 0; i < 4; ++i) {
            int idx = i * 256 + tid;
            int node = idx & 63, c = idx >> 6;
            int gn = base + node; if (gn > NN - 1) gn = NN - 1;
            float4 a = A4[gn * 16 + c];
            if (kh && sc) {
                float4 s4 = ((const float4*)sc)[c];
                float4 h4 = ((const float4*)sh)[c];
                a.x = fmaxf(fmaf(a.x, s4.x, h4.x), 0.f);
                a.y = fmaxf(fmaf(a.y, s4.y, h4.y), 0.f);
                a.z = fmaxf(fmaf(a.z, s4.z, h4.z), 0.f);
                a.w = fmaxf(fmaf(a.w, s4.w, h4.w), 0.f);
            }
            int k0 = c * 4;
            Alds[(k0 + 0) * 64 + node] = a.x;
            Alds[(k0 + 1) * 64 + node] = a.y;
            Alds[(k0 + 2) * 64 + node] = a.z;
            Alds[(k0 + 3) * 64 + node] = a.w;
        }
        __syncthreads();
#pragma unroll 8
        for (int k = 0; k < 64; ++k) {
            const float4 a = *(const float4*)(Alds + k * 64 + (ng << 2));
            const float4 w = *(const float4*)(Wlds + k * 64 + (fg << 2));
            const float av[4] = {a.x, a.y, a.z, a.w};
            const float wv[4] = {w.x, w.y, w.z, w.w};
#pragma unroll
            for (int i = 0; i < 4; ++i)
#pragma unroll
                for (int j = 0; j < 4; ++j)
                    acc[i][j] = fmaf(av[i], wv[j], acc[i][j]);
        }
    }

    const float4 b4 = ((const float4*)bias)[fg];
    float ss[4];
#pragma unroll
    for (int i = 0; i < 4; ++i) {
        acc[i][0] += b4.x; acc[i][1] += b4.y; acc[i][2] += b4.z; acc[i][3] += b4.w;
        ss[i] = acc[i][0] * acc[i][0] + acc[i][1] * acc[i][1] +
                acc[i][2] * acc[i][2] + acc[i][3] * acc[i][3];
    }
#pragma unroll
    for (int m = 1; m <= 8; m <<= 1) {
#pragma unroll
        for (int i = 0; i < 4; ++i) ss[i] += __shfl_xor(ss[i], m, 64);
    }
    float sj[4] = {0.f, 0.f, 0.f, 0.f}, qj[4] = {0.f, 0.f, 0.f, 0.f};
#pragma unroll
    for (int i = 0; i < 4; ++i) {
        float inv = 1.0f / fmaxf(sqrtf(ss[i]), 1e-12f);
        int gn = base + (ng << 2) + i;
        bool valid = (gn < NN);
        float o0 = acc[i][0] * inv, o1 = acc[i][1] * inv;
        float o2 = acc[i][2] * inv, o3 = acc[i][3] * inv;
        if (valid) {
            ((float4*)out)[gn * 16 + fg] = make_float4(o0, o1, o2, o3);
            if (outbf)
                outbf[gn * 16 + fg] = make_ushort4(bf16_of(o0), bf16_of(o1),
                                                   bf16_of(o2), bf16_of(o3));
            sj[0] += o0; sj[1] += o1; sj[2] += o2; sj[3] += o3;
            qj[0] += o0 * o0; qj[1] += o1 * o1; qj[2] += o2 * o2; qj[3] += o3 * o3;
        }
    }
#pragma unroll
    for (int m = 16; m <= 32; m <<= 1) {
#pragma unroll
        for (int j = 0; j < 4; ++j) {
            sj[j] += __shfl_xor(sj[j], m, 64);
            qj[j] += __shfl_xor(qj[j], m, 64);
        }
    }
    __syncthreads();
    float* sblk = Alds;
    float* qblk = Alds + 64;
    if (tid < 128) Alds[tid] = 0.0f;
    __syncthreads();
    if ((tid & 63) < 16) {
#pragma unroll
        for (int j = 0; j < 4; ++j) {
            atomicAdd(&sblk[fg * 4 + j], sj[j]);
            atomicAdd(&qblk[fg * 4 + j], qj[j]);
        }
    }
    __syncthreads();
    if (tid < 64) {
        atomicAdd(&sumf[tid], sblk[tid]);
        atomicAdd(&ssqf[tid], qblk[tid]);
    }
}

// ---------------- BN finalize ----------------

__global__ void k_bnfin(const float* __restrict__ sumf, const float* __restrict__ ssqf,
                        const float* __restrict__ g, const float* __restrict__ be,
                        float* __restrict__ scale, float* __restrict__ shift) {
    int f = threadIdx.x;  // 64
    float mu = sumf[f] / (float)NN;
    float var = ssqf[f] / (float)NN - mu * mu;
    var = fmaxf(var, 0.0f);
    float sc = g[f] / sqrtf(var + 1e-5f);
    scale[f] = sc;
    shift[f] = be[f] - mu * sc;
}

// ---------------- layer-3 projection: z = relu(bn2(h2raw)) @ [Wl3;Wr3]^T ----------------
__global__ __launch_bounds__(256)
void k_project(const float* __restrict__ h,
               const float* __restrict__ sc, const float* __restrict__ sh,
               const float* __restrict__ Wl, const float* __restrict__ Wr,
               const float* __restrict__ bias,
               float* __restrict__ zl, float* __restrict__ zr) {
    __shared__ float Alds[64 * 128];
    __shared__ float Wlds[64 * 32];
    const int tid = threadIdx.x;
    const int base = blockIdx.x * 128;

#pragma unroll
    for (int i = 0; i < 8; ++i) {
        int idx = i * 256 + tid;
        int f = idx & 31, k = idx >> 5;
        float v = 0.0f;
        if (f < 16) { if (f < 10) v = Wl[f * 64 + k]; }
        else        { if (f - 16 < 10) v = Wr[(f - 16) * 64 + k]; }
        Wlds[k * 32 + f] = v;
    }
    {
        const float4* h4 = (const float4*)h;
        const float4* sc4p = (const float4*)sc;
        const float4* sh4p = (const float4*)sh;
#pragma unroll
        for (int i = 0; i < 8; ++i) {
            int idx = i * 256 + tid;
            int node = idx & 127, c = idx >> 7;
            int gn = base + node; if (gn > NN - 1) gn = NN - 1;
            float4 a = h4[gn * 16 + c];
            float4 s4 = sc4p[c], t4 = sh4p[c];
            a.x = fmaxf(fmaf(a.x, s4.x, t4.x), 0.f);
            a.y = fmaxf(fmaf(a.y, s4.y, t4.y), 0.f);
            a.z = fmaxf(fmaf(a.z, s4.z, t4.z), 0.f);
            a.w = fmaxf(fmaf(a.w, s4.w, t4.w), 0.f);
            int k0 = c * 4;
            Alds[(k0 + 0) * 128 + node] = a.x;
            Alds[(k0 + 1) * 128 + node] = a.y;
            Alds[(k0 + 2) * 128 + node] = a.z;
            Alds[(k0 + 3) * 128 + node] = a.w;
        }
    }
    __syncthreads();

    const int fg = tid & 7;
    const int ng = tid >> 3;

    float acc[4][4] = {};
#pragma unroll 4
    for (int k = 0; k < 64; ++k) {
        const float4 a = *(const float4*)(Alds + k * 128 + (ng << 2));
        const float4 w = *(const float4*)(Wlds + k * 32 + (fg << 2));
        const float av[4] = {a.x, a.y, a.z, a.w};
        const float wv[4] = {w.x, w.y, w.z, w.w};
#pragma unroll
        for (int i = 0; i < 4; ++i)
#pragma unroll
            for (int j = 0; j < 4; ++j)
                acc[i][j] = fmaf(av[i], wv[j], acc[i][j]);
    }

    if (fg == 3 || fg == 7) return;
    float4* dst = (fg < 4) ? (float4*)zl : (float4*)zr;
    int fq = (fg < 4) ? fg : fg - 4;
    float bx = 0.f, by = 0.f, bz = 0.f, bw = 0.f;
    if (fg >= 4) {
        int f0 = fq * 4;
        bx = (f0 + 0 < 10) ? bias[f0 + 0] : 0.f;
        by = (f0 + 1 < 10) ? bias[f0 + 1] : 0.f;
        bz = (f0 + 2 < 10) ? bias[f0 + 2] : 0.f;
        bw = (f0 + 3 < 10) ? bias[f0 + 3] : 0.f;
    }
#pragma unroll
    for (int i = 0; i < 4; ++i) {
        int gn = base + (ng << 2) + i;
        if (gn < NN)
            dst[gn * 3 + fq] = make_float4(acc[i][0] + bx, acc[i][1] + by,
                                           acc[i][2] + bz, acc[i][3] + bw);
    }
}

// ---------------- layer-3 aggregation (10-dim): out = mean(zl[src]) + zr ----------------
__global__ __launch_bounds__(256)
void k_agg10(const int* __restrict__ rs, const int* __restrict__ esrc,
             const float* __restrict__ zl, const float* __restrict__ zr,
             float* __restrict__ out) {
    int gid = blockIdx.x * 256 + threadIdx.x;
    unsigned node = (unsigned)gid / 3u;
    int j = gid - (int)node * 3;
    if (node >= NN) return;
    int s0 = rs[node], s1 = rs[node + 1];
    const float4* zl4 = (const float4*)zl;
    float4 acc = make_float4(0.f, 0.f, 0.f, 0.f);
    for (int p = s0; p < s1; ++p) {
        float4 v = zl4[esrc[p] * 3 + j];
        acc.x += v.x; acc.y += v.y; acc.z += v.z; acc.w += v.w;
    }
    int cnt = s1 - s0; if (cnt < 1) cnt = 1;
    float inv = 1.0f / (float)cnt;
    float4 r = ((const float4*)zr)[node * 3 + j];
    r.x = fmaf(acc.x, inv, r.x); r.y = fmaf(acc.y, inv, r.y);
    r.z = fmaf(acc.z, inv, r.z); r.w = fmaf(acc.w, inv, r.w);
    float2* o2 = (float2*)(out + (size_t)node * 10);
    if (j < 2) {
        o2[j * 2 + 0] = make_float2(r.x, r.y);
        o2[j * 2 + 1] = make_float2(r.z, r.w);
    } else {
        o2[4] = make_float2(r.x, r.y);
    }
}

// ---------------- launch ----------------

extern "C" void kernel_launch(void* const* d_in, const int* in_sizes, int n_in,
                              void* d_out, int out_size, void* d_ws, size_t ws_size,
                              hipStream_t stream) {
    const float* x   = (const float*)d_in[0];
    const int*   ei  = (const int*)d_in[1];
    const float* Wl1 = (const float*)d_in[2];
    const float* Wr1 = (const float*)d_in[3];
    const float* b1  = (const float*)d_in[4];
    const float* g1  = (const float*)d_in[5];
    const float* be1 = (const float*)d_in[6];
    const float* Wl2 = (const float*)d_in[7];
    const float* Wr2 = (const float*)d_in[8];
    const float* b2  = (const float*)d_in[9];
    const float* g2  = (const float*)d_in[10];
    const float* be2 = (const float*)d_in[11];
    const float* Wl3 = (const float*)d_in[12];
    const float* Wr3 = (const float*)d_in[13];
    const float* b3  = (const float*)d_in[14];
    float* out = (float*)d_out;

    char* w = (char*)d_ws;
    auto alloc = [&](size_t bytes) -> void* {
        void* p = (void*)w;
        w += (bytes + 255) & ~(size_t)255;
        return p;
    };
    int*   ccount = (int*)alloc(256 * 4);
    int*   cbase  = (int*)alloc(256 * 4);
    int*   gcur   = (int*)alloc(256 * 4);
    int*   rs     = (int*)alloc((size_t)(NN + 1) * 4);
    int*   esrc   = (int*)alloc((size_t)EE * 4);
    float* mean   = (float*)alloc((size_t)NN * 64 * 4);
    float* h1     = (float*)alloc((size_t)NN * 64 * 4);
    unsigned short* bftab = (unsigned short*)alloc((size_t)NN * 64 * 2);  // xbf then h1bf
    float* stats  = (float*)alloc(256 * 4);  // sum1, ssq1, sum2, ssq2
    float* scsh   = (float*)alloc(256 * 4);  // scale1, shift1, scale2, shift2
    int2*  pairs  = (int2*)mean;             // aliases mean (dead before mean written)
    float* zl     = mean;                    // aliases mean (dead after layer-2 sage64)
    float* zr     = mean + (size_t)NN * 12;

    hipMemsetAsync(ccount, 0, 256 * 4, stream);
    hipMemsetAsync(stats, 0, 256 * 4, stream);

    k_ccount<<<NCH, 256, 0, stream>>>(ei, ccount);
    k_cscan<<<1, 256, 0, stream>>>(ccount, cbase, gcur);
    k_coarse<<<NCH, 256, 0, stream>>>(ei, gcur, pairs);
    k_fine<<<NBKT, 512, 0, stream>>>(cbase, pairs, rs, esrc);
    k_tobf<<<(NN * 16 + 255) / 256, 256, 0, stream>>>((const float4*)x, (ushort4*)bftab);

    const int aggBlocks  = (NN * 64) / 256;      // 25000 (1 wave / node)
    const int sageBlocks = (NN + 63) / 64;       // 1563
    const int projBlocks = (NN + 127) / 128;     // 782
    const int a10Blocks  = (NN * 3 + 255) / 256; // 1172

    // layer 1 (gathers bf16 x; sage64 writes h1 fp32 + bf16)
    k_aggbf<<<aggBlocks, 256, 0, stream>>>(bftab, rs, esrc, mean, nullptr, nullptr);
    k_sage64<<<sageBlocks, 256, 0, stream>>>(mean, x, Wl1, Wr1, b1, h1, (ushort4*)bftab,
                                             stats + 0, stats + 64, nullptr, nullptr);
    k_bnfin<<<1, 64, 0, stream>>>(stats + 0, stats + 64, g1, be1, scsh + 0, scsh + 64);

    // layer 2 (gathers bf16 h1 with fused BN1+ReLU; h2raw overwrites h1)
    k_aggbf<<<aggBlocks, 256, 0, stream>>>(bftab, rs, esrc, mean, scsh + 0, scsh + 64);
    k_sage64<<<sageBlocks, 256, 0, stream>>>(mean, h1, Wl2, Wr2, b2, h1, nullptr,
                                             stats + 128, stats + 192, scsh + 0, scsh + 64);
    k_bnfin<<<1, 64, 0, stream>>>(stats + 128, stats + 192, g2, be2, scsh + 128, scsh + 192);

    // layer 3: project (BN2+ReLU fused) then 10-dim aggregate
    k_project<<<projBlocks, 256, 0, stream>>>(h1, scsh + 128, scsh + 192,
                                              Wl3, Wr3, b3, zl, zr);
    k_agg10<<<a10Blocks, 256, 0, stream>>>(rs, esrc, zl, zr, out);
}